// Round 2
// baseline (843.427 us; speedup 1.0000x reference)
//
#include <hip/hip_runtime.h>
#include <hip/hip_bf16.h>

#define N_NODES 50000
#define E_EDGES 800000
#define EP_EDGES 850000   // E + N self loops
#define IN_DIM 160
#define HEADS 4
#define HID 64
#define C1 256            // HEADS*HID
#define NEG_SLOPE 0.2f
#define BN_EPS 1e-5f

__device__ __forceinline__ float b2f(ushort u) {
    return __uint_as_float(((unsigned)u) << 16);
}
__device__ __forceinline__ ushort f2b(float f) {
    __hip_bfloat16 h = __float2bfloat16(f);
    return *reinterpret_cast<ushort*>(&h);
}

// ---------------- runtime dtype detection ----------------
// flags[0]: 1 if float tensors are fp32 on device, 0 if bf16
// flags[1]: 1 if edge_index is int64 on device, 0 if int32
__global__ void detect_k(const ushort* __restrict__ xraw,
                         const int* __restrict__ eraw,
                         int* __restrict__ flags) {
    int lane = threadIdx.x;  // 64 threads
    int good = 0, nz = 0;
    for (int i = lane; i < 256; i += 64) {
        float a = fabsf(b2f(xraw[2 * i]));       // even 16-bit slots
        good += (a > 1e-6f && a < 1e6f) ? 1 : 0; // bf16 x~N(0,1): ~100%; fp32 mantissa words: ~15%
        nz += (eraw[2 * i + 1] != 0) ? 1 : 0;    // int64 high words are all 0
    }
    #pragma unroll
    for (int off = 32; off > 0; off >>= 1) {
        good += __shfl_xor(good, off);
        nz += __shfl_xor(nz, off);
    }
    if (lane == 0) {
        flags[0] = (good < 192) ? 1 : 0;
        flags[1] = (nz == 0) ? 1 : 0;
    }
}

// ---------------- canonicalize x -> bf16 ----------------
__global__ void cvt_x_k(const void* __restrict__ src, ushort* __restrict__ dst,
                        const int* __restrict__ flags) {
    int i = blockIdx.x * 256 + threadIdx.x;
    if (i >= N_NODES * IN_DIM) return;
    dst[i] = flags[0] ? f2b(((const float*)src)[i]) : ((const ushort*)src)[i];
}

// ---------------- canonicalize 24 small param tensors -> bf16 region ----------------
struct PP { const void* p[24]; };

__global__ void cvt_params_k(PP pp, ushort* __restrict__ dst,
                             const int* __restrict__ flags) {
    const int SIZES[24] = {40960, 256, 40960, 256, 256, 256, 256, 256, 256, 256,
                           16384, 64, 16384, 64, 64, 64, 64, 64, 64, 64,
                           10240, 64, 64, 1};
    const int OFFS[24] = {0, 40960, 41216, 82176, 82432, 82688, 82944, 83200, 83456, 83712,
                          83968, 100352, 100416, 116800, 116864, 116928, 116992, 117056, 117120, 117184,
                          117248, 127488, 127552, 127616};
    int t = blockIdx.x;
    int sz = SIZES[t], off = OFFS[t];
    bool f32 = flags[0] != 0;
    const float* pf = (const float*)pp.p[t];
    const ushort* pu = (const ushort*)pp.p[t];
    for (int i = threadIdx.x; i < sz; i += blockDim.x)
        dst[off + i] = f32 ? f2b(pf[i]) : pu[i];
}

// ---------------- canonicalize edge_index -> int32 ----------------
__global__ void cvt_e_k(const int* __restrict__ src, int* __restrict__ dst,
                        const int* __restrict__ flags) {
    int i = blockIdx.x * 256 + threadIdx.x;
    if (i >= 2 * E_EDGES) return;
    dst[i] = flags[1] ? src[2 * i] : src[i];
}

// ---------------- CSR build ----------------
__global__ void zero_deg_k(int* deg) {
    int i = blockIdx.x * 256 + threadIdx.x;
    if (i < N_NODES) deg[i] = 0;
}

__global__ void hist_k(const int* __restrict__ ei, int* __restrict__ deg) {
    int e = blockIdx.x * 256 + threadIdx.x;
    if (e >= EP_EDGES) return;
    int dst = (e < E_EDGES) ? ei[E_EDGES + e] : (e - E_EDGES);
    atomicAdd(&deg[dst], 1);
}

__global__ __launch_bounds__(1024) void scan1_k(const int* __restrict__ deg,
                                                int* __restrict__ exc,
                                                int* __restrict__ bsum) {
    __shared__ int s[1024];
    int i = blockIdx.x * 1024 + threadIdx.x;
    int v = (i < N_NODES) ? deg[i] : 0;
    s[threadIdx.x] = v;
    __syncthreads();
    for (int off = 1; off < 1024; off <<= 1) {
        int t = (threadIdx.x >= off) ? s[threadIdx.x - off] : 0;
        __syncthreads();
        s[threadIdx.x] += t;
        __syncthreads();
    }
    if (i < N_NODES) exc[i] = s[threadIdx.x] - v;
    if (threadIdx.x == 1023) bsum[blockIdx.x] = s[1023];
}

__global__ void scan2_k(int* __restrict__ bsum, int nb) {
    int lane = threadIdx.x;  // single wave of 64
    int v = (lane < nb) ? bsum[lane] : 0;
    int orig = v;
    #pragma unroll
    for (int d = 1; d < 64; d <<= 1) {
        int t = __shfl_up(v, d);
        if (lane >= d) v += t;
    }
    if (lane < nb) bsum[lane] = v - orig;
}

__global__ void scan3_k(int* __restrict__ row_ptr, const int* __restrict__ bsum,
                        int* __restrict__ rowcur) {
    int i = blockIdx.x * 256 + threadIdx.x;
    if (i >= N_NODES) return;
    int rp = row_ptr[i] + bsum[i >> 10];
    row_ptr[i] = rp;
    rowcur[i] = rp;
    if (i == 0) row_ptr[N_NODES] = EP_EDGES;
}

__global__ void scatter_k(const int* __restrict__ ei, int* __restrict__ rowcur,
                          int* __restrict__ col) {
    int e = blockIdx.x * 256 + threadIdx.x;
    if (e >= EP_EDGES) return;
    int src, dst;
    if (e < E_EDGES) { src = ei[e]; dst = ei[E_EDGES + e]; }
    else             { src = e - E_EDGES; dst = src; }
    int pos = atomicAdd(&rowcur[dst], 1);
    col[pos] = src;
}

// ---------------- SIMT GEMM: out[M,Nc](bf16) = A[M,K](bf16) @ W[K,Nc](bf16) + bias ----------------
__global__ __launch_bounds__(256) void gemm_bias_k(const ushort* __restrict__ A,
                                                   const ushort* __restrict__ W,
                                                   const ushort* __restrict__ bias,
                                                   ushort* __restrict__ out,
                                                   int M, int K, int Nc) {
    __shared__ float As[32][68];  // [kk][row]
    __shared__ float Bs[32][68];  // [kk][col]
    const int tid = threadIdx.x;
    const int tx = tid & 15, ty = tid >> 4;
    const int tx4 = tx * 4, ty4 = ty * 4;
    const int row0 = blockIdx.x * 64, col0 = blockIdx.y * 64;
    float acc[4][4] = {};
    for (int k0 = 0; k0 < K; k0 += 32) {
        #pragma unroll
        for (int it = 0; it < 2; ++it) {
            int idx = it * 256 + tid;
            int r = idx >> 3, cq = (idx & 7) << 2;
            int gr = row0 + r;
            float v0 = 0.f, v1 = 0.f, v2 = 0.f, v3 = 0.f;
            if (gr < M) {
                ushort4 u = *reinterpret_cast<const ushort4*>(&A[(size_t)gr * K + k0 + cq]);
                v0 = b2f(u.x); v1 = b2f(u.y); v2 = b2f(u.z); v3 = b2f(u.w);
            }
            As[cq + 0][r] = v0; As[cq + 1][r] = v1;
            As[cq + 2][r] = v2; As[cq + 3][r] = v3;
            int kk = idx >> 4, wq = (idx & 15) << 2;
            ushort4 w = *reinterpret_cast<const ushort4*>(&W[(size_t)(k0 + kk) * Nc + col0 + wq]);
            Bs[kk][wq + 0] = b2f(w.x); Bs[kk][wq + 1] = b2f(w.y);
            Bs[kk][wq + 2] = b2f(w.z); Bs[kk][wq + 3] = b2f(w.w);
        }
        __syncthreads();
        #pragma unroll
        for (int kk = 0; kk < 32; ++kk) {
            float a[4], b[4];
            #pragma unroll
            for (int i = 0; i < 4; ++i) a[i] = As[kk][ty4 + i];
            #pragma unroll
            for (int j = 0; j < 4; ++j) b[j] = Bs[kk][tx4 + j];
            #pragma unroll
            for (int i = 0; i < 4; ++i)
                #pragma unroll
                for (int j = 0; j < 4; ++j)
                    acc[i][j] = fmaf(a[i], b[j], acc[i][j]);
        }
        __syncthreads();
    }
    float bb[4];
    #pragma unroll
    for (int j = 0; j < 4; ++j) bb[j] = b2f(bias[col0 + tx4 + j]);
    #pragma unroll
    for (int i = 0; i < 4; ++i) {
        int gr = row0 + ty4 + i;
        if (gr < M) {
            ushort4 v;
            v.x = f2b(acc[i][0] + bb[0]);
            v.y = f2b(acc[i][1] + bb[1]);
            v.z = f2b(acc[i][2] + bb[2]);
            v.w = f2b(acc[i][3] + bb[3]);
            *reinterpret_cast<ushort4*>(&out[(size_t)gr * Nc + col0 + tx4]) = v;
        }
    }
}

// ---------------- conv1: pull aggregation + softmax + bias + BN1 + relu -> bf16 ----------------
__global__ __launch_bounds__(256) void conv1_k(const ushort* __restrict__ xl,
                                               const ushort* __restrict__ xr,
                                               const int* __restrict__ row_ptr,
                                               const int* __restrict__ col,
                                               const ushort* __restrict__ att,    // [4][64]
                                               const ushort* __restrict__ bias1,
                                               const ushort* __restrict__ g1,
                                               const ushort* __restrict__ b1,
                                               const ushort* __restrict__ m1,
                                               const ushort* __restrict__ v1,
                                               ushort* __restrict__ h1out) {
    const int n = blockIdx.x;
    const int h = threadIdx.x >> 6;
    const int lane = threadIdx.x & 63;
    const int c = h * 64 + lane;
    const float xrd = b2f(xr[(size_t)n * C1 + c]);
    const float attv = b2f(att[c]);
    const int e0 = row_ptr[n], e1 = row_ptr[n + 1];
    float acc = 0.f, den = 0.f;
    for (int i = e0; i < e1; ++i) {
        const int s = col[i];
        const float xld = b2f(xl[(size_t)s * C1 + c]);
        float t = xld + xrd;
        t = (t > 0.f) ? t : NEG_SLOPE * t;
        float p = t * attv;
        #pragma unroll
        for (int off = 32; off > 0; off >>= 1) p += __shfl_xor(p, off);
        const float w = __expf(fminf(p, 60.f));
        acc = fmaf(w, xld, acc);
        den += w;
    }
    float o = acc / den + b2f(bias1[c]);
    float sc = b2f(g1[c]) * rsqrtf(b2f(v1[c]) + BN_EPS);
    float hv = (o - b2f(m1[c])) * sc + b2f(b1[c]);
    hv = fmaxf(hv, 0.f);
    h1out[(size_t)n * C1 + c] = f2b(hv);
}

// ---------------- conv2 + BN2 + relu + skip + output linear ----------------
__global__ __launch_bounds__(256) void conv2_k(const ushort* __restrict__ xl,
                                               const ushort* __restrict__ xr,
                                               const ushort* __restrict__ xskip,
                                               const int* __restrict__ row_ptr,
                                               const int* __restrict__ col,
                                               const ushort* __restrict__ att2,
                                               const ushort* __restrict__ bias2,
                                               const ushort* __restrict__ g2,
                                               const ushort* __restrict__ bb2,
                                               const ushort* __restrict__ m2,
                                               const ushort* __restrict__ v2,
                                               const ushort* __restrict__ Wo,
                                               const ushort* __restrict__ bo,
                                               void* __restrict__ out,
                                               const int* __restrict__ flags) {
    const int n = blockIdx.x * 4 + (threadIdx.x >> 6);
    if (n >= N_NODES) return;
    const int lane = threadIdx.x & 63;
    const float xrd = b2f(xr[(size_t)n * HID + lane]);
    const float attv = b2f(att2[lane]);
    const int e0 = row_ptr[n], e1 = row_ptr[n + 1];
    float acc = 0.f, den = 0.f;
    for (int i = e0; i < e1; ++i) {
        const int s = col[i];
        const float xld = b2f(xl[(size_t)s * HID + lane]);
        float t = xld + xrd;
        t = (t > 0.f) ? t : NEG_SLOPE * t;
        float p = t * attv;
        #pragma unroll
        for (int off = 32; off > 0; off >>= 1) p += __shfl_xor(p, off);
        const float w = __expf(fminf(p, 60.f));
        acc = fmaf(w, xld, acc);
        den += w;
    }
    float o = acc / den + b2f(bias2[lane]);
    float sc = b2f(g2[lane]) * rsqrtf(b2f(v2[lane]) + BN_EPS);
    float hv = (o - b2f(m2[lane])) * sc + b2f(bb2[lane]);
    hv = fmaxf(hv, 0.f);
    float hf = hv + b2f(xskip[(size_t)n * HID + lane]);
    float dotp = hf * b2f(Wo[lane]);
    #pragma unroll
    for (int off = 32; off > 0; off >>= 1) dotp += __shfl_xor(dotp, off);
    if (lane == 0) {
        float r = dotp + b2f(bo[0]);
        if (flags[0]) ((float*)out)[n] = r;
        else          ((ushort*)out)[n] = f2b(r);
    }
}

extern "C" void kernel_launch(void* const* d_in, const int* in_sizes, int n_in,
                              void* d_out, int out_size, void* d_ws, size_t ws_size,
                              hipStream_t stream) {
    char* ws = (char*)d_ws;
    size_t off = 0;
    auto alloc = [&](size_t bytes) -> void* {
        void* p = ws + off;
        off += (bytes + 255) & ~(size_t)255;
        return p;
    };
    int*    flags   = (int*)alloc(256);
    ushort* params  = (ushort*)alloc((size_t)127617 * 2);        // canonical bf16 params
    ushort* x_c     = (ushort*)alloc((size_t)N_NODES * IN_DIM * 2); // 16 MB
    int*    ei32    = (int*)alloc((size_t)2 * E_EDGES * 4);      // 6.4 MB
    int*    row_ptr = (int*)alloc((size_t)(N_NODES + 1) * 4);
    int*    rowcur  = (int*)alloc((size_t)N_NODES * 4);
    int*    deg     = (int*)alloc((size_t)N_NODES * 4);
    int*    colbuf  = (int*)alloc((size_t)EP_EDGES * 4);         // 3.4 MB
    int*    bsum    = (int*)alloc(64 * 4);
    ushort* xl1     = (ushort*)alloc((size_t)N_NODES * C1 * 2);  // 25.6 MB
    ushort* xr1     = (ushort*)alloc((size_t)N_NODES * C1 * 2);  // 25.6 MB
    ushort* xskip   = (ushort*)alloc((size_t)N_NODES * HID * 2); // 6.4 MB
    ushort* h1      = (ushort*)alloc((size_t)N_NODES * C1 * 2);  // 25.6 MB
    ushort* xl2     = (ushort*)alloc((size_t)N_NODES * HID * 2);
    ushort* xr2     = (ushort*)alloc((size_t)N_NODES * HID * 2);

    // canonical param pointers (see OFFS in cvt_params_k)
    ushort* Wl1c   = params + 0;
    ushort* bl1c   = params + 40960;
    ushort* Wr1c   = params + 41216;
    ushort* br1c   = params + 82176;
    ushort* att1c  = params + 82432;
    ushort* bias1c = params + 82688;
    ushort* g1c    = params + 82944;
    ushort* b1c    = params + 83200;
    ushort* m1c    = params + 83456;
    ushort* v1c    = params + 83712;
    ushort* Wl2c   = params + 83968;
    ushort* bl2c   = params + 100352;
    ushort* Wr2c   = params + 100416;
    ushort* br2c   = params + 116800;
    ushort* att2c  = params + 116864;
    ushort* bias2c = params + 116928;
    ushort* g2c    = params + 116992;
    ushort* b2c    = params + 117056;
    ushort* m2c    = params + 117120;
    ushort* v2c    = params + 117184;
    ushort* Wsc    = params + 117248;
    ushort* bsc    = params + 127488;
    ushort* Woc    = params + 127552;
    ushort* boc    = params + 127616;

    // ---- detect dtypes & canonicalize ----
    detect_k<<<1, 64, 0, stream>>>((const ushort*)d_in[0], (const int*)d_in[1], flags);
    cvt_x_k<<<(N_NODES * IN_DIM + 255) / 256, 256, 0, stream>>>(d_in[0], x_c, flags);
    PP pp;
    for (int i = 0; i < 24; ++i) pp.p[i] = d_in[2 + i];
    cvt_params_k<<<24, 256, 0, stream>>>(pp, params, flags);
    cvt_e_k<<<(2 * E_EDGES + 255) / 256, 256, 0, stream>>>((const int*)d_in[1], ei32, flags);

    const int NB_N = (N_NODES + 255) / 256;        // 196
    const int NB_E = (EP_EDGES + 255) / 256;       // 3321
    const int NB_S = (N_NODES + 1023) / 1024;      // 49

    // ---- CSR build ----
    zero_deg_k<<<NB_N, 256, 0, stream>>>(deg);
    hist_k<<<NB_E, 256, 0, stream>>>(ei32, deg);
    scan1_k<<<NB_S, 1024, 0, stream>>>(deg, row_ptr, bsum);
    scan2_k<<<1, 64, 0, stream>>>(bsum, NB_S);
    scan3_k<<<NB_N, 256, 0, stream>>>(row_ptr, bsum, rowcur);
    scatter_k<<<NB_E, 256, 0, stream>>>(ei32, rowcur, colbuf);

    // ---- layer-1 linear transforms (+ skip) ----
    const int GM = (N_NODES + 63) / 64;  // 782
    gemm_bias_k<<<dim3(GM, 4), 256, 0, stream>>>(x_c, Wl1c, bl1c, xl1, N_NODES, IN_DIM, C1);
    gemm_bias_k<<<dim3(GM, 4), 256, 0, stream>>>(x_c, Wr1c, br1c, xr1, N_NODES, IN_DIM, C1);
    gemm_bias_k<<<dim3(GM, 1), 256, 0, stream>>>(x_c, Wsc, bsc, xskip, N_NODES, IN_DIM, HID);

    // ---- conv1 edge aggregation + BN1 + relu ----
    conv1_k<<<N_NODES, 256, 0, stream>>>(xl1, xr1, row_ptr, colbuf, att1c, bias1c,
                                         g1c, b1c, m1c, v1c, h1);

    // ---- layer-2 linear transforms ----
    gemm_bias_k<<<dim3(GM, 1), 256, 0, stream>>>(h1, Wl2c, bl2c, xl2, N_NODES, C1, HID);
    gemm_bias_k<<<dim3(GM, 1), 256, 0, stream>>>(h1, Wr2c, br2c, xr2, N_NODES, C1, HID);

    // ---- conv2 + BN2 + relu + skip + output linear ----
    conv2_k<<<(N_NODES + 3) / 4, 256, 0, stream>>>(xl2, xr2, xskip, row_ptr, colbuf,
                                                   att2c, bias2c, g2c, b2c, m2c, v2c,
                                                   Woc, boc, d_out, flags);
}

// Round 3
// 640.559 us; speedup vs baseline: 1.3167x; 1.3167x over previous
//
#include <hip/hip_runtime.h>
#include <hip/hip_bf16.h>

#define N_NODES 50000
#define E_EDGES 800000
#define EP_EDGES 850000   // E + N self loops
#define IN_DIM 160
#define HEADS 4
#define HID 64
#define C1 256            // HEADS*HID
#define NEG_SLOPE 0.2f
#define BN_EPS 1e-5f

typedef __attribute__((ext_vector_type(8))) short bf16x8;
typedef __attribute__((ext_vector_type(4))) float f32x4;

__device__ __forceinline__ float b2f(ushort u) {
    return __uint_as_float(((unsigned)u) << 16);
}
__device__ __forceinline__ ushort f2b(float f) {
    __hip_bfloat16 h = __float2bfloat16(f);
    return *reinterpret_cast<ushort*>(&h);
}

// ---------------- runtime dtype detection ----------------
// flags[0]: 1 if float tensors are fp32 on device, 0 if bf16
// flags[1]: 1 if edge_index is int64 on device, 0 if int32
__global__ void detect_k(const ushort* __restrict__ xraw,
                         const int* __restrict__ eraw,
                         int* __restrict__ flags) {
    int lane = threadIdx.x;  // 64 threads
    int good = 0, nz = 0;
    for (int i = lane; i < 256; i += 64) {
        float a = fabsf(b2f(xraw[2 * i]));
        good += (a > 1e-6f && a < 1e6f) ? 1 : 0;
        nz += (eraw[2 * i + 1] != 0) ? 1 : 0;
    }
    #pragma unroll
    for (int off = 32; off > 0; off >>= 1) {
        good += __shfl_xor(good, off);
        nz += __shfl_xor(nz, off);
    }
    if (lane == 0) {
        flags[0] = (good < 192) ? 1 : 0;
        flags[1] = (nz == 0) ? 1 : 0;
    }
}

// ---------------- canonicalize x -> bf16 ----------------
__global__ void cvt_x_k(const void* __restrict__ src, ushort* __restrict__ dst,
                        const int* __restrict__ flags) {
    int i = blockIdx.x * 256 + threadIdx.x;
    if (i >= N_NODES * IN_DIM) return;
    dst[i] = flags[0] ? f2b(((const float*)src)[i]) : ((const ushort*)src)[i];
}

// ---------------- canonicalize 24 small param tensors -> bf16 region ----------------
struct PP { const void* p[24]; };

__global__ void cvt_params_k(PP pp, ushort* __restrict__ dst,
                             const int* __restrict__ flags) {
    const int SIZES[24] = {40960, 256, 40960, 256, 256, 256, 256, 256, 256, 256,
                           16384, 64, 16384, 64, 64, 64, 64, 64, 64, 64,
                           10240, 64, 64, 1};
    const int OFFS[24] = {0, 40960, 41216, 82176, 82432, 82688, 82944, 83200, 83456, 83712,
                          83968, 100352, 100416, 116800, 116864, 116928, 116992, 117056, 117120, 117184,
                          117248, 127488, 127552, 127616};
    int t = blockIdx.x;
    int sz = SIZES[t], off = OFFS[t];
    bool f32 = flags[0] != 0;
    const float* pf = (const float*)pp.p[t];
    const ushort* pu = (const ushort*)pp.p[t];
    for (int i = threadIdx.x; i < sz; i += blockDim.x)
        dst[off + i] = f32 ? f2b(pf[i]) : pu[i];
}

// ---------------- canonicalize edge_index -> int32 ----------------
__global__ void cvt_e_k(const int* __restrict__ src, int* __restrict__ dst,
                        const int* __restrict__ flags) {
    int i = blockIdx.x * 256 + threadIdx.x;
    if (i >= 2 * E_EDGES) return;
    dst[i] = flags[1] ? src[2 * i] : src[i];
}

// ---------------- weight swizzle into MFMA B-fragment order ----------------
// dst chunk f = kb*(N/16)+t holds, per lane l, B[kb*32+(l>>4)*8+j][t*16+(l&15)], j=0..7
__global__ void swz_k(const ushort* __restrict__ W, ushort* __restrict__ dst,
                      int K, int N) {
    int idx = blockIdx.x * 256 + threadIdx.x;
    int NT = N >> 4;
    int total = (K >> 5) * NT * 64;
    if (idx >= total) return;
    int lane = idx & 63;
    int ft = idx >> 6;
    int kb = ft / NT, t = ft - kb * NT;
    int q = lane >> 4, m = lane & 15;
    ushort* d = dst + (size_t)idx * 8;
    #pragma unroll
    for (int j = 0; j < 8; ++j)
        d[j] = W[(size_t)(kb * 32 + q * 8 + j) * N + t * 16 + m];
}

// ---------------- CSR build ----------------
__global__ void zero_deg_k(int* deg) {
    int i = blockIdx.x * 256 + threadIdx.x;
    if (i < N_NODES) deg[i] = 0;
}

__global__ void hist_k(const int* __restrict__ ei, int* __restrict__ deg) {
    int e = blockIdx.x * 256 + threadIdx.x;
    if (e >= EP_EDGES) return;
    int dst = (e < E_EDGES) ? ei[E_EDGES + e] : (e - E_EDGES);
    atomicAdd(&deg[dst], 1);
}

__global__ __launch_bounds__(1024) void scan1_k(const int* __restrict__ deg,
                                                int* __restrict__ exc,
                                                int* __restrict__ bsum) {
    __shared__ int s[1024];
    int i = blockIdx.x * 1024 + threadIdx.x;
    int v = (i < N_NODES) ? deg[i] : 0;
    s[threadIdx.x] = v;
    __syncthreads();
    for (int off = 1; off < 1024; off <<= 1) {
        int t = (threadIdx.x >= off) ? s[threadIdx.x - off] : 0;
        __syncthreads();
        s[threadIdx.x] += t;
        __syncthreads();
    }
    if (i < N_NODES) exc[i] = s[threadIdx.x] - v;
    if (threadIdx.x == 1023) bsum[blockIdx.x] = s[1023];
}

__global__ void scan2_k(int* __restrict__ bsum, int nb) {
    int lane = threadIdx.x;  // single wave of 64
    int v = (lane < nb) ? bsum[lane] : 0;
    int orig = v;
    #pragma unroll
    for (int d = 1; d < 64; d <<= 1) {
        int t = __shfl_up(v, d);
        if (lane >= d) v += t;
    }
    if (lane < nb) bsum[lane] = v - orig;
}

__global__ void scan3_k(int* __restrict__ row_ptr, const int* __restrict__ bsum,
                        int* __restrict__ rowcur) {
    int i = blockIdx.x * 256 + threadIdx.x;
    if (i >= N_NODES) return;
    int rp = row_ptr[i] + bsum[i >> 10];
    row_ptr[i] = rp;
    rowcur[i] = rp;
    if (i == 0) row_ptr[N_NODES] = EP_EDGES;
}

__global__ void scatter_k(const int* __restrict__ ei, int* __restrict__ rowcur,
                          int* __restrict__ col) {
    int e = blockIdx.x * 256 + threadIdx.x;
    if (e >= EP_EDGES) return;
    int src, dst;
    if (e < E_EDGES) { src = ei[e]; dst = ei[E_EDGES + e]; }
    else             { src = e - E_EDGES; dst = src; }
    int pos = atomicAdd(&rowcur[dst], 1);
    col[pos] = src;
}

// ---------------- MFMA GEMM: out[M,N](bf16) = A[M,K](bf16) @ W(swizzled) + bias ----------------
// Wave = 16 rows x N cols. No LDS, no barriers; B-frags stream from L2-resident swz buffer.
template<int K, int NT>
__global__ __launch_bounds__(256) void gemm_mfma_k(const ushort* __restrict__ A,
                                                   const ushort* __restrict__ Bswz,
                                                   const ushort* __restrict__ bias,
                                                   ushort* __restrict__ out,
                                                   int M) {
    constexpr int KB = K / 32;
    constexpr int N = NT * 16;
    const int wave = threadIdx.x >> 6;
    const int lane = threadIdx.x & 63;
    const int row0 = blockIdx.x * 64 + wave * 16;
    if (row0 >= M) return;
    const int am = lane & 15, aq = lane >> 4;
    int arow = row0 + am;
    if (arow >= M) arow = M - 1;
    const ushort* aptr = A + (size_t)arow * K + aq * 8;
    const bf16x8* bp = (const bf16x8*)Bswz;
    f32x4 acc[NT] = {};
    #pragma unroll
    for (int kb = 0; kb < KB; ++kb) {
        bf16x8 af = *(const bf16x8*)(aptr + kb * 32);
        #pragma unroll
        for (int t = 0; t < NT; ++t) {
            bf16x8 bf = bp[(kb * NT + t) * 64 + lane];
            acc[t] = __builtin_amdgcn_mfma_f32_16x16x32_bf16(af, bf, acc[t], 0, 0, 0);
        }
    }
    const int cn = lane & 15, cq = lane >> 4;
    #pragma unroll
    for (int t = 0; t < NT; ++t) {
        float bb = b2f(bias[t * 16 + cn]);
        #pragma unroll
        for (int r = 0; r < 4; ++r) {
            int grow = row0 + cq * 4 + r;
            if (grow < M)
                out[(size_t)grow * N + t * 16 + cn] = f2b(acc[t][r] + bb);
        }
    }
}

// ---------------- conv1: edge-pair pull aggregation + softmax + bias + BN1 + relu ----------------
// Block = node; wave = head; 32-lane halves each own one edge; lane holds 2 channels.
__global__ __launch_bounds__(256) void conv1_k(const ushort* __restrict__ xl,
                                               const ushort* __restrict__ xr,
                                               const int* __restrict__ row_ptr,
                                               const int* __restrict__ col,
                                               const ushort* __restrict__ att,
                                               const ushort* __restrict__ bias1,
                                               const ushort* __restrict__ g1,
                                               const ushort* __restrict__ b1,
                                               const ushort* __restrict__ m1,
                                               const ushort* __restrict__ v1,
                                               ushort* __restrict__ h1out) {
    const int n = blockIdx.x;
    const int h = threadIdx.x >> 6;
    const int half = (threadIdx.x >> 5) & 1;
    const int sl = threadIdx.x & 31;
    const int cp = h * 32 + sl;              // uint index into the 128-uint row
    const uint* xl32 = (const uint*)xl;
    const uint xru = ((const uint*)xr)[(size_t)n * 128 + cp];
    const float xr0 = b2f((ushort)(xru & 0xffffu)), xr1 = b2f((ushort)(xru >> 16));
    const uint atu = ((const uint*)att)[cp];
    const float at0 = b2f((ushort)(atu & 0xffffu)), at1 = b2f((ushort)(atu >> 16));
    const int e0 = row_ptr[n], e1 = row_ptr[n + 1];
    float acc0 = 0.f, acc1 = 0.f, den = 0.f;
    for (int i = e0; i < e1; i += 2) {
        const int j = i + half;
        const bool valid = j < e1;
        const int s = col[valid ? j : e1 - 1];
        const uint xu = xl32[(size_t)s * 128 + cp];
        const float x0 = b2f((ushort)(xu & 0xffffu)), x1 = b2f((ushort)(xu >> 16));
        float t0 = x0 + xr0; t0 = (t0 > 0.f) ? t0 : NEG_SLOPE * t0;
        float t1 = x1 + xr1; t1 = (t1 > 0.f) ? t1 : NEG_SLOPE * t1;
        float p = fmaf(t0, at0, t1 * at1);
        p += __shfl_xor(p, 1);
        p += __shfl_xor(p, 2);
        p += __shfl_xor(p, 4);
        p += __shfl_xor(p, 8);
        p += __shfl_xor(p, 16);
        const float w = valid ? __expf(fminf(p, 60.f)) : 0.f;
        acc0 = fmaf(w, x0, acc0);
        acc1 = fmaf(w, x1, acc1);
        den += w;
    }
    acc0 += __shfl_xor(acc0, 32);
    acc1 += __shfl_xor(acc1, 32);
    den  += __shfl_xor(den, 32);
    if (half == 0) {
        const int c0 = 2 * cp, c1 = c0 + 1;
        float o0 = acc0 / den + b2f(bias1[c0]);
        float o1 = acc1 / den + b2f(bias1[c1]);
        float s0 = b2f(g1[c0]) * rsqrtf(b2f(v1[c0]) + BN_EPS);
        float s1 = b2f(g1[c1]) * rsqrtf(b2f(v1[c1]) + BN_EPS);
        float h0 = fmaxf((o0 - b2f(m1[c0])) * s0 + b2f(b1[c0]), 0.f);
        float h1v = fmaxf((o1 - b2f(m1[c1])) * s1 + b2f(b1[c1]), 0.f);
        ((uint*)h1out)[(size_t)n * 128 + cp] = (uint)f2b(h0) | ((uint)f2b(h1v) << 16);
    }
}

// ---------------- conv2 + BN2 + relu + skip + output linear ----------------
__global__ __launch_bounds__(256) void conv2_k(const ushort* __restrict__ xl,
                                               const ushort* __restrict__ xr,
                                               const ushort* __restrict__ xskip,
                                               const int* __restrict__ row_ptr,
                                               const int* __restrict__ col,
                                               const ushort* __restrict__ att2,
                                               const ushort* __restrict__ bias2,
                                               const ushort* __restrict__ g2,
                                               const ushort* __restrict__ bb2,
                                               const ushort* __restrict__ m2,
                                               const ushort* __restrict__ v2,
                                               const ushort* __restrict__ Wo,
                                               const ushort* __restrict__ bo,
                                               void* __restrict__ out,
                                               const int* __restrict__ flags) {
    const int n = blockIdx.x * 4 + (threadIdx.x >> 6);
    if (n >= N_NODES) return;
    const int half = (threadIdx.x >> 5) & 1;
    const int sl = threadIdx.x & 31;         // uint index into 32-uint row
    const uint* xl32 = (const uint*)xl;
    const uint xru = ((const uint*)xr)[(size_t)n * 32 + sl];
    const float xr0 = b2f((ushort)(xru & 0xffffu)), xr1 = b2f((ushort)(xru >> 16));
    const uint atu = ((const uint*)att2)[sl];
    const float at0 = b2f((ushort)(atu & 0xffffu)), at1 = b2f((ushort)(atu >> 16));
    const int e0 = row_ptr[n], e1 = row_ptr[n + 1];
    float acc0 = 0.f, acc1 = 0.f, den = 0.f;
    for (int i = e0; i < e1; i += 2) {
        const int j = i + half;
        const bool valid = j < e1;
        const int s = col[valid ? j : e1 - 1];
        const uint xu = xl32[(size_t)s * 32 + sl];
        const float x0 = b2f((ushort)(xu & 0xffffu)), x1 = b2f((ushort)(xu >> 16));
        float t0 = x0 + xr0; t0 = (t0 > 0.f) ? t0 : NEG_SLOPE * t0;
        float t1 = x1 + xr1; t1 = (t1 > 0.f) ? t1 : NEG_SLOPE * t1;
        float p = fmaf(t0, at0, t1 * at1);
        p += __shfl_xor(p, 1);
        p += __shfl_xor(p, 2);
        p += __shfl_xor(p, 4);
        p += __shfl_xor(p, 8);
        p += __shfl_xor(p, 16);
        const float w = valid ? __expf(fminf(p, 60.f)) : 0.f;
        acc0 = fmaf(w, x0, acc0);
        acc1 = fmaf(w, x1, acc1);
        den += w;
    }
    acc0 += __shfl_xor(acc0, 32);
    acc1 += __shfl_xor(acc1, 32);
    den  += __shfl_xor(den, 32);
    // all lanes now hold full sums; compute 2 channels each, dot with Wo
    const int c0 = 2 * sl, c1 = c0 + 1;
    float o0 = acc0 / den + b2f(bias2[c0]);
    float o1 = acc1 / den + b2f(bias2[c1]);
    float s0 = b2f(g2[c0]) * rsqrtf(b2f(v2[c0]) + BN_EPS);
    float s1 = b2f(g2[c1]) * rsqrtf(b2f(v2[c1]) + BN_EPS);
    float h0 = fmaxf((o0 - b2f(m2[c0])) * s0 + b2f(bb2[c0]), 0.f);
    float h1v = fmaxf((o1 - b2f(m2[c1])) * s1 + b2f(bb2[c1]), 0.f);
    const uint sku = ((const uint*)xskip)[(size_t)n * 32 + sl];
    const float hf0 = h0 + b2f((ushort)(sku & 0xffffu));
    const float hf1 = h1v + b2f((ushort)(sku >> 16));
    const uint wou = ((const uint*)Wo)[sl];
    float d = fmaf(hf0, b2f((ushort)(wou & 0xffffu)),
                   hf1 * b2f((ushort)(wou >> 16)));
    d += __shfl_xor(d, 1);
    d += __shfl_xor(d, 2);
    d += __shfl_xor(d, 4);
    d += __shfl_xor(d, 8);
    d += __shfl_xor(d, 16);
    if ((threadIdx.x & 63) == 0) {
        float r = d + b2f(bo[0]);
        if (flags[0]) ((float*)out)[n] = r;
        else          ((ushort*)out)[n] = f2b(r);
    }
}

extern "C" void kernel_launch(void* const* d_in, const int* in_sizes, int n_in,
                              void* d_out, int out_size, void* d_ws, size_t ws_size,
                              hipStream_t stream) {
    char* ws = (char*)d_ws;
    size_t off = 0;
    auto alloc = [&](size_t bytes) -> void* {
        void* p = ws + off;
        off += (bytes + 255) & ~(size_t)255;
        return p;
    };
    int*    flags   = (int*)alloc(256);
    ushort* params  = (ushort*)alloc((size_t)127617 * 2);
    ushort* x_c     = (ushort*)alloc((size_t)N_NODES * IN_DIM * 2);
    int*    ei32    = (int*)alloc((size_t)2 * E_EDGES * 4);
    int*    row_ptr = (int*)alloc((size_t)(N_NODES + 1) * 4);
    int*    rowcur  = (int*)alloc((size_t)N_NODES * 4);
    int*    deg     = (int*)alloc((size_t)N_NODES * 4);
    int*    colbuf  = (int*)alloc((size_t)EP_EDGES * 4);
    int*    bsum    = (int*)alloc(64 * 4);
    ushort* xl1     = (ushort*)alloc((size_t)N_NODES * C1 * 2);
    ushort* xr1     = (ushort*)alloc((size_t)N_NODES * C1 * 2);
    ushort* xskip   = (ushort*)alloc((size_t)N_NODES * HID * 2);
    ushort* h1      = (ushort*)alloc((size_t)N_NODES * C1 * 2);
    ushort* xl2     = (ushort*)alloc((size_t)N_NODES * HID * 2);
    ushort* xr2     = (ushort*)alloc((size_t)N_NODES * HID * 2);
    ushort* swzWl1  = (ushort*)alloc((size_t)IN_DIM * C1 * 2);
    ushort* swzWr1  = (ushort*)alloc((size_t)IN_DIM * C1 * 2);
    ushort* swzWs   = (ushort*)alloc((size_t)IN_DIM * HID * 2);
    ushort* swzWl2  = (ushort*)alloc((size_t)C1 * HID * 2);
    ushort* swzWr2  = (ushort*)alloc((size_t)C1 * HID * 2);

    ushort* Wl1c   = params + 0;
    ushort* bl1c   = params + 40960;
    ushort* Wr1c   = params + 41216;
    ushort* br1c   = params + 82176;
    ushort* att1c  = params + 82432;
    ushort* bias1c = params + 82688;
    ushort* g1c    = params + 82944;
    ushort* b1c    = params + 83200;
    ushort* m1c    = params + 83456;
    ushort* v1c    = params + 83712;
    ushort* Wl2c   = params + 83968;
    ushort* bl2c   = params + 100352;
    ushort* Wr2c   = params + 100416;
    ushort* br2c   = params + 116800;
    ushort* att2c  = params + 116864;
    ushort* bias2c = params + 116928;
    ushort* g2c    = params + 116992;
    ushort* b2c    = params + 117056;
    ushort* m2c    = params + 117120;
    ushort* v2c    = params + 117184;
    ushort* Wsc    = params + 117248;
    ushort* bsc    = params + 127488;
    ushort* Woc    = params + 127552;
    ushort* boc    = params + 127616;

    // ---- detect dtypes & canonicalize ----
    detect_k<<<1, 64, 0, stream>>>((const ushort*)d_in[0], (const int*)d_in[1], flags);
    cvt_x_k<<<(N_NODES * IN_DIM + 255) / 256, 256, 0, stream>>>(d_in[0], x_c, flags);
    PP pp;
    for (int i = 0; i < 24; ++i) pp.p[i] = d_in[2 + i];
    cvt_params_k<<<24, 256, 0, stream>>>(pp, params, flags);
    cvt_e_k<<<(2 * E_EDGES + 255) / 256, 256, 0, stream>>>((const int*)d_in[1], ei32, flags);

    // ---- weight swizzles for MFMA ----
    swz_k<<<(5 * 16 * 64 + 255) / 256, 256, 0, stream>>>(Wl1c, swzWl1, IN_DIM, C1);
    swz_k<<<(5 * 16 * 64 + 255) / 256, 256, 0, stream>>>(Wr1c, swzWr1, IN_DIM, C1);
    swz_k<<<(5 * 4 * 64 + 255) / 256, 256, 0, stream>>>(Wsc, swzWs, IN_DIM, HID);
    swz_k<<<(8 * 4 * 64 + 255) / 256, 256, 0, stream>>>(Wl2c, swzWl2, C1, HID);
    swz_k<<<(8 * 4 * 64 + 255) / 256, 256, 0, stream>>>(Wr2c, swzWr2, C1, HID);

    const int NB_N = (N_NODES + 255) / 256;        // 196
    const int NB_E = (EP_EDGES + 255) / 256;       // 3321
    const int NB_S = (N_NODES + 1023) / 1024;      // 49

    // ---- CSR build ----
    zero_deg_k<<<NB_N, 256, 0, stream>>>(deg);
    hist_k<<<NB_E, 256, 0, stream>>>(ei32, deg);
    scan1_k<<<NB_S, 1024, 0, stream>>>(deg, row_ptr, bsum);
    scan2_k<<<1, 64, 0, stream>>>(bsum, NB_S);
    scan3_k<<<NB_N, 256, 0, stream>>>(row_ptr, bsum, rowcur);
    scatter_k<<<NB_E, 256, 0, stream>>>(ei32, rowcur, colbuf);

    // ---- layer-1 linear transforms (+ skip), MFMA ----
    const int GB = (N_NODES + 63) / 64;  // 782 blocks of 4 waves x 16 rows
    gemm_mfma_k<IN_DIM, 16><<<GB, 256, 0, stream>>>(x_c, swzWl1, bl1c, xl1, N_NODES);
    gemm_mfma_k<IN_DIM, 16><<<GB, 256, 0, stream>>>(x_c, swzWr1, br1c, xr1, N_NODES);
    gemm_mfma_k<IN_DIM, 4><<<GB, 256, 0, stream>>>(x_c, swzWs, bsc, xskip, N_NODES);

    // ---- conv1 edge aggregation + BN1 + relu ----
    conv1_k<<<N_NODES, 256, 0, stream>>>(xl1, xr1, row_ptr, colbuf, att1c, bias1c,
                                         g1c, b1c, m1c, v1c, h1);

    // ---- layer-2 linear transforms, MFMA ----
    gemm_mfma_k<C1, 4><<<GB, 256, 0, stream>>>(h1, swzWl2, bl2c, xl2, N_NODES);
    gemm_mfma_k<C1, 4><<<GB, 256, 0, stream>>>(h1, swzWr2, br2c, xr2, N_NODES);

    // ---- conv2 + BN2 + relu + skip + output linear ----
    conv2_k<<<(N_NODES + 3) / 4, 256, 0, stream>>>(xl2, xr2, xskip, row_ptr, colbuf,
                                                   att2c, bias2c, g2c, b2c, m2c, v2c,
                                                   Woc, boc, d_out, flags);
}

// Round 4
// 551.469 us; speedup vs baseline: 1.5294x; 1.1615x over previous
//
#include <hip/hip_runtime.h>
#include <hip/hip_bf16.h>

#define N_NODES 50000
#define E_EDGES 800000
#define EP_EDGES 850000   // E + N self loops
#define IN_DIM 160
#define HEADS 4
#define HID 64
#define C1 256            // HEADS*HID
#define NEG_SLOPE 0.2f
#define BN_EPS 1e-5f

typedef __attribute__((ext_vector_type(8))) short bf16x8;
typedef __attribute__((ext_vector_type(4))) float f32x4;

__device__ __forceinline__ float b2f(ushort u) {
    return __uint_as_float(((unsigned)u) << 16);
}
__device__ __forceinline__ ushort f2b(float f) {
    __hip_bfloat16 h = __float2bfloat16(f);
    return *reinterpret_cast<ushort*>(&h);
}
// unpack packed bf16 pair (low, high) from a uint
__device__ __forceinline__ float lo16(uint u) { return __uint_as_float(u << 16); }
__device__ __forceinline__ float hi16(uint u) { return __uint_as_float(u & 0xffff0000u); }

// ---------------- runtime dtype detection ----------------
// flags[0]: 1 if float tensors are fp32 on device, 0 if bf16
// flags[1]: 1 if edge_index is int64 on device, 0 if int32
__global__ void detect_k(const ushort* __restrict__ xraw,
                         const int* __restrict__ eraw,
                         int* __restrict__ flags) {
    int lane = threadIdx.x;  // 64 threads
    int good = 0, nz = 0;
    for (int i = lane; i < 256; i += 64) {
        float a = fabsf(b2f(xraw[2 * i]));
        good += (a > 1e-6f && a < 1e6f) ? 1 : 0;
        nz += (eraw[2 * i + 1] != 0) ? 1 : 0;
    }
    #pragma unroll
    for (int off = 32; off > 0; off >>= 1) {
        good += __shfl_xor(good, off);
        nz += __shfl_xor(nz, off);
    }
    if (lane == 0) {
        flags[0] = (good < 192) ? 1 : 0;
        flags[1] = (nz == 0) ? 1 : 0;
    }
}

// ---------------- canonicalize x -> bf16 (also zeroes deg) ----------------
__global__ void cvt_x_k(const void* __restrict__ src, ushort* __restrict__ dst,
                        const int* __restrict__ flags, int* __restrict__ deg) {
    int i = blockIdx.x * 256 + threadIdx.x;
    if (i < N_NODES) deg[i] = 0;
    if (i >= N_NODES * IN_DIM) return;
    dst[i] = flags[0] ? f2b(((const float*)src)[i]) : ((const ushort*)src)[i];
}

// ---------------- canonicalize 24 small param tensors -> bf16 region ----------------
struct PP { const void* p[24]; };

__global__ void cvt_params_k(PP pp, ushort* __restrict__ dst,
                             const int* __restrict__ flags) {
    const int SIZES[24] = {40960, 256, 40960, 256, 256, 256, 256, 256, 256, 256,
                           16384, 64, 16384, 64, 64, 64, 64, 64, 64, 64,
                           10240, 64, 64, 1};
    const int OFFS[24] = {0, 40960, 41216, 82176, 82432, 82688, 82944, 83200, 83456, 83712,
                          83968, 100352, 100416, 116800, 116864, 116928, 116992, 117056, 117120, 117184,
                          117248, 127488, 127552, 127616};
    int t = blockIdx.x;
    int sz = SIZES[t], off = OFFS[t];
    bool f32 = flags[0] != 0;
    const float* pf = (const float*)pp.p[t];
    const ushort* pu = (const ushort*)pp.p[t];
    for (int i = threadIdx.x; i < sz; i += blockDim.x)
        dst[off + i] = f32 ? f2b(pf[i]) : pu[i];
}

// ---------------- fused weight swizzle into MFMA B-fragment order ----------------
// per segment: chunk f = kb*NT + t holds, per lane l, B[kb*32+(l>>4)*8+j][t*16+(l&15)], j=0..7
struct SWZ {
    const ushort* W[5];
    ushort* D[5];
    int NT[5];
    int base[5];   // cumulative thread base per segment
    int total;
};

__global__ void swz_all_k(SWZ s) {
    int idx = blockIdx.x * 256 + threadIdx.x;
    if (idx >= s.total) return;
    int seg = 0;
    #pragma unroll
    for (int k = 1; k < 5; ++k) seg += (idx >= s.base[k]) ? 1 : 0;
    int li = idx - s.base[seg];
    int NT = s.NT[seg];
    int N = NT << 4;
    int lane = li & 63;
    int ft = li >> 6;
    int kb = ft / NT, t = ft - kb * NT;
    int q = lane >> 4, m = lane & 15;
    const ushort* W = s.W[seg];
    ushort* d = s.D[seg] + (size_t)li * 8;
    #pragma unroll
    for (int j = 0; j < 8; ++j)
        d[j] = W[(size_t)(kb * 32 + q * 8 + j) * N + t * 16 + m];
}

// ---------------- CSR build (reads raw edge_index, flag-dependent stride) ----------------
__global__ void hist_k(const int* __restrict__ ei, const int* __restrict__ flags,
                       int* __restrict__ deg) {
    int e = blockIdx.x * 256 + threadIdx.x;
    if (e >= EP_EDGES) return;
    int dst;
    if (e < E_EDGES) {
        int idx = E_EDGES + e;
        dst = flags[1] ? ei[2 * idx] : ei[idx];
    } else dst = e - E_EDGES;
    atomicAdd(&deg[dst], 1);
}

__global__ __launch_bounds__(1024) void scan1_k(const int* __restrict__ deg,
                                                int* __restrict__ exc,
                                                int* __restrict__ bsum) {
    __shared__ int s[1024];
    int i = blockIdx.x * 1024 + threadIdx.x;
    int v = (i < N_NODES) ? deg[i] : 0;
    s[threadIdx.x] = v;
    __syncthreads();
    for (int off = 1; off < 1024; off <<= 1) {
        int t = (threadIdx.x >= off) ? s[threadIdx.x - off] : 0;
        __syncthreads();
        s[threadIdx.x] += t;
        __syncthreads();
    }
    if (i < N_NODES) exc[i] = s[threadIdx.x] - v;
    if (threadIdx.x == 1023) bsum[blockIdx.x] = s[1023];
}

__global__ void scan2_k(int* __restrict__ bsum, int nb) {
    int lane = threadIdx.x;  // single wave of 64
    int v = (lane < nb) ? bsum[lane] : 0;
    int orig = v;
    #pragma unroll
    for (int d = 1; d < 64; d <<= 1) {
        int t = __shfl_up(v, d);
        if (lane >= d) v += t;
    }
    if (lane < nb) bsum[lane] = v - orig;
}

__global__ void scan3_k(int* __restrict__ row_ptr, const int* __restrict__ bsum,
                        int* __restrict__ rowcur) {
    int i = blockIdx.x * 256 + threadIdx.x;
    if (i >= N_NODES) return;
    int rp = row_ptr[i] + bsum[i >> 10];
    row_ptr[i] = rp;
    rowcur[i] = rp;
    if (i == 0) row_ptr[N_NODES] = EP_EDGES;
}

__global__ void scatter_k(const int* __restrict__ ei, const int* __restrict__ flags,
                          int* __restrict__ rowcur, int* __restrict__ col) {
    int e = blockIdx.x * 256 + threadIdx.x;
    if (e >= EP_EDGES) return;
    int src, dst;
    if (e < E_EDGES) {
        if (flags[1]) { src = ei[2 * e]; dst = ei[2 * (E_EDGES + e)]; }
        else          { src = ei[e];     dst = ei[E_EDGES + e]; }
    } else { src = e - E_EDGES; dst = src; }
    int pos = atomicAdd(&rowcur[dst], 1);
    col[pos] = src;
}

// ---------------- MFMA GEMM: out[M,N](bf16) = A[M,K](bf16) @ W(swizzled) + bias ----------------
template<int K, int NT>
__global__ __launch_bounds__(256) void gemm_mfma_k(const ushort* __restrict__ A,
                                                   const ushort* __restrict__ Bswz,
                                                   const ushort* __restrict__ bias,
                                                   ushort* __restrict__ out,
                                                   int M) {
    constexpr int KB = K / 32;
    constexpr int N = NT * 16;
    const int wave = threadIdx.x >> 6;
    const int lane = threadIdx.x & 63;
    const int row0 = blockIdx.x * 64 + wave * 16;
    if (row0 >= M) return;
    const int am = lane & 15, aq = lane >> 4;
    int arow = row0 + am;
    if (arow >= M) arow = M - 1;
    const ushort* aptr = A + (size_t)arow * K + aq * 8;
    const bf16x8* bp = (const bf16x8*)Bswz;
    f32x4 acc[NT] = {};
    #pragma unroll
    for (int kb = 0; kb < KB; ++kb) {
        bf16x8 af = *(const bf16x8*)(aptr + kb * 32);
        #pragma unroll
        for (int t = 0; t < NT; ++t) {
            bf16x8 bf = bp[(kb * NT + t) * 64 + lane];
            acc[t] = __builtin_amdgcn_mfma_f32_16x16x32_bf16(af, bf, acc[t], 0, 0, 0);
        }
    }
    const int cn = lane & 15, cq = lane >> 4;
    #pragma unroll
    for (int t = 0; t < NT; ++t) {
        float bb = b2f(bias[t * 16 + cn]);
        #pragma unroll
        for (int r = 0; r < 4; ++r) {
            int grow = row0 + cq * 4 + r;
            if (grow < M)
                out[(size_t)grow * N + t * 16 + cn] = f2b(acc[t][r] + bb);
        }
    }
}

// ---------------- conv1: 4 edges/iter, 16 lanes/edge, 4 ch/lane ----------------
// Block = node; wave = head. Software-pipelined col/xl loads.
__global__ __launch_bounds__(256) void conv1_k(const ushort* __restrict__ xl,
                                               const ushort* __restrict__ xr,
                                               const int* __restrict__ row_ptr,
                                               const int* __restrict__ col,
                                               const ushort* __restrict__ att,
                                               const ushort* __restrict__ bias1,
                                               const ushort* __restrict__ g1,
                                               const ushort* __restrict__ b1,
                                               const ushort* __restrict__ m1,
                                               const ushort* __restrict__ v1,
                                               ushort* __restrict__ h1out) {
    const int n = blockIdx.x;
    const int h = threadIdx.x >> 6;          // wave = head
    const int lane = threadIdx.x & 63;
    const int grp = lane >> 4;               // edge slot 0..3
    const int m = lane & 15;                 // channel quad
    const int cpi = h * 16 + m;              // uint2 index within 64-uint2 row
    const uint2* xl2v = (const uint2*)xl;
    const uint2 xru = ((const uint2*)xr)[(size_t)n * 64 + cpi];
    const float xr0 = lo16(xru.x), xr1 = hi16(xru.x);
    const float xr2 = lo16(xru.y), xr3 = hi16(xru.y);
    const uint2 atu = ((const uint2*)att)[cpi];
    const float at0 = lo16(atu.x), at1 = hi16(atu.x);
    const float at2 = lo16(atu.y), at3 = hi16(atu.y);
    const int e0 = row_ptr[n], e1 = row_ptr[n + 1];
    float a0 = 0.f, a1 = 0.f, a2 = 0.f, a3 = 0.f, den = 0.f;
    int jA = e0 + grp;
    int sA = col[jA < e1 ? jA : e1 - 1];
    int jB = jA + 4;
    int sB = col[jB < e1 ? jB : e1 - 1];
    for (int i = e0; i < e1; i += 4) {
        const uint2 xu = xl2v[(size_t)sA * 64 + cpi];
        const int jC = i + 8 + grp;
        const int sC = col[jC < e1 ? jC : e1 - 1];
        const bool valid = (i + grp) < e1;
        const float x0 = lo16(xu.x), x1 = hi16(xu.x);
        const float x2 = lo16(xu.y), x3 = hi16(xu.y);
        float t0 = x0 + xr0; t0 = fmaxf(t0, t0 * NEG_SLOPE);
        float t1 = x1 + xr1; t1 = fmaxf(t1, t1 * NEG_SLOPE);
        float t2 = x2 + xr2; t2 = fmaxf(t2, t2 * NEG_SLOPE);
        float t3 = x3 + xr3; t3 = fmaxf(t3, t3 * NEG_SLOPE);
        float p = fmaf(t0, at0, fmaf(t1, at1, fmaf(t2, at2, t3 * at3)));
        p += __shfl_xor(p, 1);
        p += __shfl_xor(p, 2);
        p += __shfl_xor(p, 4);
        p += __shfl_xor(p, 8);
        const float w = valid ? __expf(fminf(p, 60.f)) : 0.f;
        a0 = fmaf(w, x0, a0);
        a1 = fmaf(w, x1, a1);
        a2 = fmaf(w, x2, a2);
        a3 = fmaf(w, x3, a3);
        den += w;
        sA = sB; sB = sC;
    }
    a0 += __shfl_xor(a0, 16); a0 += __shfl_xor(a0, 32);
    a1 += __shfl_xor(a1, 16); a1 += __shfl_xor(a1, 32);
    a2 += __shfl_xor(a2, 16); a2 += __shfl_xor(a2, 32);
    a3 += __shfl_xor(a3, 16); a3 += __shfl_xor(a3, 32);
    den += __shfl_xor(den, 16); den += __shfl_xor(den, 32);
    if (lane < 16) {
        const float inv = 1.f / den;
        const uint2 biu = ((const uint2*)bias1)[cpi];
        const uint2 gu  = ((const uint2*)g1)[cpi];
        const uint2 bu  = ((const uint2*)b1)[cpi];
        const uint2 mu  = ((const uint2*)m1)[cpi];
        const uint2 vu  = ((const uint2*)v1)[cpi];
        float o0 = fmaf(a0, inv, lo16(biu.x));
        float o1 = fmaf(a1, inv, hi16(biu.x));
        float o2 = fmaf(a2, inv, lo16(biu.y));
        float o3 = fmaf(a3, inv, hi16(biu.y));
        float s0 = lo16(gu.x) * rsqrtf(lo16(vu.x) + BN_EPS);
        float s1 = hi16(gu.x) * rsqrtf(hi16(vu.x) + BN_EPS);
        float s2 = lo16(gu.y) * rsqrtf(lo16(vu.y) + BN_EPS);
        float s3 = hi16(gu.y) * rsqrtf(hi16(vu.y) + BN_EPS);
        float h0 = fmaxf((o0 - lo16(mu.x)) * s0 + lo16(bu.x), 0.f);
        float h1v = fmaxf((o1 - hi16(mu.x)) * s1 + hi16(bu.x), 0.f);
        float h2 = fmaxf((o2 - lo16(mu.y)) * s2 + lo16(bu.y), 0.f);
        float h3 = fmaxf((o3 - hi16(mu.y)) * s3 + hi16(bu.y), 0.f);
        uint2 ou;
        ou.x = (uint)f2b(h0) | ((uint)f2b(h1v) << 16);
        ou.y = (uint)f2b(h2) | ((uint)f2b(h3) << 16);
        ((uint2*)h1out)[(size_t)n * 64 + cpi] = ou;
    }
}

// ---------------- conv2 + BN2 + relu + skip + output linear ----------------
// Wave = node (4 nodes/block); 4 edges/iter, 16 lanes/edge, 4 ch/lane.
__global__ __launch_bounds__(256) void conv2_k(const ushort* __restrict__ xl,
                                               const ushort* __restrict__ xr,
                                               const ushort* __restrict__ xskip,
                                               const int* __restrict__ row_ptr,
                                               const int* __restrict__ col,
                                               const ushort* __restrict__ att2,
                                               const ushort* __restrict__ bias2,
                                               const ushort* __restrict__ g2,
                                               const ushort* __restrict__ bb2,
                                               const ushort* __restrict__ m2,
                                               const ushort* __restrict__ v2,
                                               const ushort* __restrict__ Wo,
                                               const ushort* __restrict__ bo,
                                               void* __restrict__ out,
                                               const int* __restrict__ flags) {
    const int n = blockIdx.x * 4 + (threadIdx.x >> 6);
    if (n >= N_NODES) return;
    const int lane = threadIdx.x & 63;
    const int grp = lane >> 4;
    const int m = lane & 15;                 // uint2 index within 16-uint2 row
    const uint2* xl2v = (const uint2*)xl;
    const uint2 xru = ((const uint2*)xr)[(size_t)n * 16 + m];
    const float xr0 = lo16(xru.x), xr1 = hi16(xru.x);
    const float xr2 = lo16(xru.y), xr3 = hi16(xru.y);
    const uint2 atu = ((const uint2*)att2)[m];
    const float at0 = lo16(atu.x), at1 = hi16(atu.x);
    const float at2 = lo16(atu.y), at3 = hi16(atu.y);
    const int e0 = row_ptr[n], e1 = row_ptr[n + 1];
    float a0 = 0.f, a1 = 0.f, a2 = 0.f, a3 = 0.f, den = 0.f;
    int jA = e0 + grp;
    int sA = col[jA < e1 ? jA : e1 - 1];
    int jB = jA + 4;
    int sB = col[jB < e1 ? jB : e1 - 1];
    for (int i = e0; i < e1; i += 4) {
        const uint2 xu = xl2v[(size_t)sA * 16 + m];
        const int jC = i + 8 + grp;
        const int sC = col[jC < e1 ? jC : e1 - 1];
        const bool valid = (i + grp) < e1;
        const float x0 = lo16(xu.x), x1 = hi16(xu.x);
        const float x2 = lo16(xu.y), x3 = hi16(xu.y);
        float t0 = x0 + xr0; t0 = fmaxf(t0, t0 * NEG_SLOPE);
        float t1 = x1 + xr1; t1 = fmaxf(t1, t1 * NEG_SLOPE);
        float t2 = x2 + xr2; t2 = fmaxf(t2, t2 * NEG_SLOPE);
        float t3 = x3 + xr3; t3 = fmaxf(t3, t3 * NEG_SLOPE);
        float p = fmaf(t0, at0, fmaf(t1, at1, fmaf(t2, at2, t3 * at3)));
        p += __shfl_xor(p, 1);
        p += __shfl_xor(p, 2);
        p += __shfl_xor(p, 4);
        p += __shfl_xor(p, 8);
        const float w = valid ? __expf(fminf(p, 60.f)) : 0.f;
        a0 = fmaf(w, x0, a0);
        a1 = fmaf(w, x1, a1);
        a2 = fmaf(w, x2, a2);
        a3 = fmaf(w, x3, a3);
        den += w;
        sA = sB; sB = sC;
    }
    a0 += __shfl_xor(a0, 16); a0 += __shfl_xor(a0, 32);
    a1 += __shfl_xor(a1, 16); a1 += __shfl_xor(a1, 32);
    a2 += __shfl_xor(a2, 16); a2 += __shfl_xor(a2, 32);
    a3 += __shfl_xor(a3, 16); a3 += __shfl_xor(a3, 32);
    den += __shfl_xor(den, 16); den += __shfl_xor(den, 32);
    if (lane < 16) {
        const float inv = 1.f / den;
        const uint2 biu = ((const uint2*)bias2)[m];
        const uint2 gu  = ((const uint2*)g2)[m];
        const uint2 bu  = ((const uint2*)bb2)[m];
        const uint2 mu  = ((const uint2*)m2)[m];
        const uint2 vu  = ((const uint2*)v2)[m];
        const uint2 sku = ((const uint2*)xskip)[(size_t)n * 16 + m];
        const uint2 wou = ((const uint2*)Wo)[m];
        float o0 = fmaf(a0, inv, lo16(biu.x));
        float o1 = fmaf(a1, inv, hi16(biu.x));
        float o2 = fmaf(a2, inv, lo16(biu.y));
        float o3 = fmaf(a3, inv, hi16(biu.y));
        float s0 = lo16(gu.x) * rsqrtf(lo16(vu.x) + BN_EPS);
        float s1 = hi16(gu.x) * rsqrtf(hi16(vu.x) + BN_EPS);
        float s2 = lo16(gu.y) * rsqrtf(lo16(vu.y) + BN_EPS);
        float s3 = hi16(gu.y) * rsqrtf(hi16(vu.y) + BN_EPS);
        float h0 = fmaxf((o0 - lo16(mu.x)) * s0 + lo16(bu.x), 0.f) + lo16(sku.x);
        float h1v = fmaxf((o1 - hi16(mu.x)) * s1 + hi16(bu.x), 0.f) + hi16(sku.x);
        float h2 = fmaxf((o2 - lo16(mu.y)) * s2 + lo16(bu.y), 0.f) + lo16(sku.y);
        float h3 = fmaxf((o3 - hi16(mu.y)) * s3 + hi16(bu.y), 0.f) + hi16(sku.y);
        float d = fmaf(h0, lo16(wou.x), fmaf(h1v, hi16(wou.x),
                  fmaf(h2, lo16(wou.y), h3 * hi16(wou.y))));
        d += __shfl_xor(d, 1);
        d += __shfl_xor(d, 2);
        d += __shfl_xor(d, 4);
        d += __shfl_xor(d, 8);
        if (m == 0) {
            float r = d + b2f(bo[0]);
            if (flags[0]) ((float*)out)[n] = r;
            else          ((ushort*)out)[n] = f2b(r);
        }
    }
}

extern "C" void kernel_launch(void* const* d_in, const int* in_sizes, int n_in,
                              void* d_out, int out_size, void* d_ws, size_t ws_size,
                              hipStream_t stream) {
    char* ws = (char*)d_ws;
    size_t off = 0;
    auto alloc = [&](size_t bytes) -> void* {
        void* p = ws + off;
        off += (bytes + 255) & ~(size_t)255;
        return p;
    };
    int*    flags   = (int*)alloc(256);
    ushort* params  = (ushort*)alloc((size_t)127617 * 2);
    ushort* x_c     = (ushort*)alloc((size_t)N_NODES * IN_DIM * 2);
    int*    row_ptr = (int*)alloc((size_t)(N_NODES + 1) * 4);
    int*    rowcur  = (int*)alloc((size_t)N_NODES * 4);
    int*    deg     = (int*)alloc((size_t)N_NODES * 4);
    int*    colbuf  = (int*)alloc((size_t)EP_EDGES * 4);
    int*    bsum    = (int*)alloc(64 * 4);
    ushort* xl1     = (ushort*)alloc((size_t)N_NODES * C1 * 2);
    ushort* xr1     = (ushort*)alloc((size_t)N_NODES * C1 * 2);
    ushort* xskip   = (ushort*)alloc((size_t)N_NODES * HID * 2);
    ushort* h1      = (ushort*)alloc((size_t)N_NODES * C1 * 2);
    ushort* xl2     = (ushort*)alloc((size_t)N_NODES * HID * 2);
    ushort* xr2     = (ushort*)alloc((size_t)N_NODES * HID * 2);
    ushort* swzWl1  = (ushort*)alloc((size_t)IN_DIM * C1 * 2);
    ushort* swzWr1  = (ushort*)alloc((size_t)IN_DIM * C1 * 2);
    ushort* swzWs   = (ushort*)alloc((size_t)IN_DIM * HID * 2);
    ushort* swzWl2  = (ushort*)alloc((size_t)C1 * HID * 2);
    ushort* swzWr2  = (ushort*)alloc((size_t)C1 * HID * 2);

    ushort* Wl1c   = params + 0;
    ushort* bl1c   = params + 40960;
    ushort* Wr1c   = params + 41216;
    ushort* br1c   = params + 82176;
    ushort* att1c  = params + 82432;
    ushort* bias1c = params + 82688;
    ushort* g1c    = params + 82944;
    ushort* b1c    = params + 83200;
    ushort* m1c    = params + 83456;
    ushort* v1c    = params + 83712;
    ushort* Wl2c   = params + 83968;
    ushort* bl2c   = params + 100352;
    ushort* Wr2c   = params + 100416;
    ushort* br2c   = params + 116800;
    ushort* att2c  = params + 116864;
    ushort* bias2c = params + 116928;
    ushort* g2c    = params + 116992;
    ushort* b2c    = params + 117056;
    ushort* m2c    = params + 117120;
    ushort* v2c    = params + 117184;
    ushort* Wsc    = params + 117248;
    ushort* bsc    = params + 127488;
    ushort* Woc    = params + 127552;
    ushort* boc    = params + 127616;

    // ---- detect dtypes & canonicalize ----
    detect_k<<<1, 64, 0, stream>>>((const ushort*)d_in[0], (const int*)d_in[1], flags);
    cvt_x_k<<<(N_NODES * IN_DIM + 255) / 256, 256, 0, stream>>>(d_in[0], x_c, flags, deg);
    PP pp;
    for (int i = 0; i < 24; ++i) pp.p[i] = d_in[2 + i];
    cvt_params_k<<<24, 256, 0, stream>>>(pp, params, flags);

    // ---- fused weight swizzles for MFMA ----
    // frag-thread counts: Wl1 5*16*64=5120, Wr1 5120, Ws 5*4*64=1280, Wl2 8*4*64=2048, Wr2 2048
    SWZ sw;
    sw.W[0] = Wl1c;  sw.D[0] = swzWl1; sw.NT[0] = 16; sw.base[0] = 0;
    sw.W[1] = Wr1c;  sw.D[1] = swzWr1; sw.NT[1] = 16; sw.base[1] = 5120;
    sw.W[2] = Wsc;   sw.D[2] = swzWs;  sw.NT[2] = 4;  sw.base[2] = 10240;
    sw.W[3] = Wl2c;  sw.D[3] = swzWl2; sw.NT[3] = 4;  sw.base[3] = 11520;
    sw.W[4] = Wr2c;  sw.D[4] = swzWr2; sw.NT[4] = 4;  sw.base[4] = 13568;
    sw.total = 15616;
    swz_all_k<<<(15616 + 255) / 256, 256, 0, stream>>>(sw);

    const int NB_N = (N_NODES + 255) / 256;        // 196
    const int NB_E = (EP_EDGES + 255) / 256;       // 3321
    const int NB_S = (N_NODES + 1023) / 1024;      // 49

    // ---- CSR build (reads raw edge_index) ----
    const int* ei_raw = (const int*)d_in[1];
    hist_k<<<NB_E, 256, 0, stream>>>(ei_raw, flags, deg);
    scan1_k<<<NB_S, 1024, 0, stream>>>(deg, row_ptr, bsum);
    scan2_k<<<1, 64, 0, stream>>>(bsum, NB_S);
    scan3_k<<<NB_N, 256, 0, stream>>>(row_ptr, bsum, rowcur);
    scatter_k<<<NB_E, 256, 0, stream>>>(ei_raw, flags, rowcur, colbuf);

    // ---- layer-1 linear transforms (+ skip), MFMA ----
    const int GB = (N_NODES + 63) / 64;  // 782 blocks of 4 waves x 16 rows
    gemm_mfma_k<IN_DIM, 16><<<GB, 256, 0, stream>>>(x_c, swzWl1, bl1c, xl1, N_NODES);
    gemm_mfma_k<IN_DIM, 16><<<GB, 256, 0, stream>>>(x_c, swzWr1, br1c, xr1, N_NODES);
    gemm_mfma_k<IN_DIM, 4><<<GB, 256, 0, stream>>>(x_c, swzWs, bsc, xskip, N_NODES);

    // ---- conv1 edge aggregation + BN1 + relu ----
    conv1_k<<<N_NODES, 256, 0, stream>>>(xl1, xr1, row_ptr, colbuf, att1c, bias1c,
                                         g1c, b1c, m1c, v1c, h1);

    // ---- layer-2 linear transforms, MFMA ----
    gemm_mfma_k<C1, 4><<<GB, 256, 0, stream>>>(h1, swzWl2, bl2c, xl2, N_NODES);
    gemm_mfma_k<C1, 4><<<GB, 256, 0, stream>>>(h1, swzWr2, br2c, xr2, N_NODES);

    // ---- conv2 + BN2 + relu + skip + output linear ----
    conv2_k<<<(N_NODES + 3) / 4, 256, 0, stream>>>(xl2, xr2, xskip, row_ptr, colbuf,
                                                   att2c, bias2c, g2c, b2c, m2c, v2c,
                                                   Woc, boc, d_out, flags);
}

// Round 5
// 517.729 us; speedup vs baseline: 1.6291x; 1.0652x over previous
//
#include <hip/hip_runtime.h>
#include <hip/hip_bf16.h>

#define N_NODES 50000
#define E_EDGES 800000
#define EP_EDGES 850000   // E + N self loops
#define IN_DIM 160
#define HEADS 4
#define HID 64
#define C1 256            // HEADS*HID
#define NEG_SLOPE 0.2f
#define BN_EPS 1e-5f

typedef __attribute__((ext_vector_type(8))) short bf16x8;
typedef __attribute__((ext_vector_type(4))) float f32x4;

__device__ __forceinline__ float b2f(ushort u) {
    return __uint_as_float(((unsigned)u) << 16);
}
__device__ __forceinline__ ushort f2b(float f) {
    __hip_bfloat16 h = __float2bfloat16(f);
    return *reinterpret_cast<ushort*>(&h);
}
__device__ __forceinline__ float lo16(uint u) { return __uint_as_float(u << 16); }
__device__ __forceinline__ float hi16(uint u) { return __uint_as_float(u & 0xffff0000u); }

// DPP-based add of a permuted copy: pure VALU pipe (no ds_bpermute / lgkm wait)
template<int CTRL>
__device__ __forceinline__ float dpp_add(float p) {
    int t = __builtin_amdgcn_update_dpp(0, __float_as_int(p), CTRL, 0xf, 0xf, true);
    return p + __int_as_float(t);
}
// sum over each 16-lane row; all 16 lanes get the row total
__device__ __forceinline__ float row16_sum(float p) {
    p = dpp_add<0xB1>(p);    // quad_perm xor1
    p = dpp_add<0x4E>(p);    // quad_perm xor2
    p = dpp_add<0x124>(p);   // row_ror:4
    p = dpp_add<0x128>(p);   // row_ror:8
    return p;
}

// ---------------- runtime dtype detection ----------------
// flags[0]: 1 if float tensors are fp32 on device, 0 if bf16
// flags[1]: 1 if edge_index is int64 on device, 0 if int32
__global__ void detect_k(const ushort* __restrict__ xraw,
                         const int* __restrict__ eraw,
                         int* __restrict__ flags) {
    int lane = threadIdx.x;  // 64 threads
    int good = 0, nz = 0;
    for (int i = lane; i < 256; i += 64) {
        float a = fabsf(b2f(xraw[2 * i]));
        good += (a > 1e-6f && a < 1e6f) ? 1 : 0;
        nz += (eraw[2 * i + 1] != 0) ? 1 : 0;
    }
    #pragma unroll
    for (int off = 32; off > 0; off >>= 1) {
        good += __shfl_xor(good, off);
        nz += __shfl_xor(nz, off);
    }
    if (lane == 0) {
        flags[0] = (good < 192) ? 1 : 0;
        flags[1] = (nz == 0) ? 1 : 0;
    }
}

// ---------------- canonicalize x -> bf16 (also zeroes deg) ----------------
__global__ void cvt_x_k(const void* __restrict__ src, ushort* __restrict__ dst,
                        const int* __restrict__ flags, int* __restrict__ deg) {
    int i = blockIdx.x * 256 + threadIdx.x;
    if (i < N_NODES) deg[i] = 0;
    if (i >= N_NODES * IN_DIM) return;
    dst[i] = flags[0] ? f2b(((const float*)src)[i]) : ((const ushort*)src)[i];
}

// ---------------- canonicalize 24 small param tensors -> bf16 region ----------------
struct PP { const void* p[24]; };

__global__ void cvt_params_k(PP pp, ushort* __restrict__ dst,
                             const int* __restrict__ flags) {
    const int SIZES[24] = {40960, 256, 40960, 256, 256, 256, 256, 256, 256, 256,
                           16384, 64, 16384, 64, 64, 64, 64, 64, 64, 64,
                           10240, 64, 64, 1};
    const int OFFS[24] = {0, 40960, 41216, 82176, 82432, 82688, 82944, 83200, 83456, 83712,
                          83968, 100352, 100416, 116800, 116864, 116928, 116992, 117056, 117120, 117184,
                          117248, 127488, 127552, 127616};
    int t = blockIdx.x;
    int sz = SIZES[t], off = OFFS[t];
    bool f32 = flags[0] != 0;
    const float* pf = (const float*)pp.p[t];
    const ushort* pu = (const ushort*)pp.p[t];
    for (int i = threadIdx.x; i < sz; i += blockDim.x)
        dst[off + i] = f32 ? f2b(pf[i]) : pu[i];
}

// ---------------- fused weight swizzle into MFMA B-fragment order ----------------
struct SWZ {
    const ushort* W[5];
    ushort* D[5];
    int NT[5];
    int base[5];
    int total;
};

__global__ void swz_all_k(SWZ s) {
    int idx = blockIdx.x * 256 + threadIdx.x;
    if (idx >= s.total) return;
    int seg = 0;
    #pragma unroll
    for (int k = 1; k < 5; ++k) seg += (idx >= s.base[k]) ? 1 : 0;
    int li = idx - s.base[seg];
    int NT = s.NT[seg];
    int N = NT << 4;
    int lane = li & 63;
    int ft = li >> 6;
    int kb = ft / NT, t = ft - kb * NT;
    int q = lane >> 4, m = lane & 15;
    const ushort* W = s.W[seg];
    ushort* d = s.D[seg] + (size_t)li * 8;
    #pragma unroll
    for (int j = 0; j < 8; ++j)
        d[j] = W[(size_t)(kb * 32 + q * 8 + j) * N + t * 16 + m];
}

// ---------------- CSR build (reads raw edge_index, flag-dependent stride) ----------------
__global__ void hist_k(const int* __restrict__ ei, const int* __restrict__ flags,
                       int* __restrict__ deg) {
    int e = blockIdx.x * 256 + threadIdx.x;
    if (e >= EP_EDGES) return;
    int dst;
    if (e < E_EDGES) {
        int idx = E_EDGES + e;
        dst = flags[1] ? ei[2 * idx] : ei[idx];
    } else dst = e - E_EDGES;
    atomicAdd(&deg[dst], 1);
}

__global__ __launch_bounds__(1024) void scan1_k(const int* __restrict__ deg,
                                                int* __restrict__ exc,
                                                int* __restrict__ bsum) {
    __shared__ int s[1024];
    int i = blockIdx.x * 1024 + threadIdx.x;
    int v = (i < N_NODES) ? deg[i] : 0;
    s[threadIdx.x] = v;
    __syncthreads();
    for (int off = 1; off < 1024; off <<= 1) {
        int t = (threadIdx.x >= off) ? s[threadIdx.x - off] : 0;
        __syncthreads();
        s[threadIdx.x] += t;
        __syncthreads();
    }
    if (i < N_NODES) exc[i] = s[threadIdx.x] - v;
    if (threadIdx.x == 1023) bsum[blockIdx.x] = s[1023];
}

__global__ void scan2_k(int* __restrict__ bsum, int nb) {
    int lane = threadIdx.x;  // single wave of 64
    int v = (lane < nb) ? bsum[lane] : 0;
    int orig = v;
    #pragma unroll
    for (int d = 1; d < 64; d <<= 1) {
        int t = __shfl_up(v, d);
        if (lane >= d) v += t;
    }
    if (lane < nb) bsum[lane] = v - orig;
}

__global__ void scan3_k(int* __restrict__ row_ptr, const int* __restrict__ bsum,
                        int* __restrict__ rowcur) {
    int i = blockIdx.x * 256 + threadIdx.x;
    if (i >= N_NODES) return;
    int rp = row_ptr[i] + bsum[i >> 10];
    row_ptr[i] = rp;
    rowcur[i] = rp;
    if (i == 0) row_ptr[N_NODES] = EP_EDGES;
}

__global__ void scatter_k(const int* __restrict__ ei, const int* __restrict__ flags,
                          int* __restrict__ rowcur, int* __restrict__ col) {
    int e = blockIdx.x * 256 + threadIdx.x;
    if (e >= EP_EDGES) return;
    int src, dst;
    if (e < E_EDGES) {
        if (flags[1]) { src = ei[2 * e]; dst = ei[2 * (E_EDGES + e)]; }
        else          { src = ei[e];     dst = ei[E_EDGES + e]; }
    } else { src = e - E_EDGES; dst = src; }
    int pos = atomicAdd(&rowcur[dst], 1);
    col[pos] = src;
}

// ---------------- fused layer-1 MFMA GEMM: xl1(256) + xr1(256) + xskip(64) ----------------
__global__ __launch_bounds__(256) void gemm3_k(const ushort* __restrict__ A,
                                               const ushort* __restrict__ B1,
                                               const ushort* __restrict__ B2,
                                               const ushort* __restrict__ B3,
                                               const ushort* __restrict__ bi1,
                                               const ushort* __restrict__ bi2,
                                               const ushort* __restrict__ bi3,
                                               ushort* __restrict__ o1,
                                               ushort* __restrict__ o2,
                                               ushort* __restrict__ o3,
                                               int M) {
    const int wave = threadIdx.x >> 6;
    const int lane = threadIdx.x & 63;
    const int row0 = blockIdx.x * 64 + wave * 16;
    if (row0 >= M) return;
    int arow = row0 + (lane & 15);
    if (arow >= M) arow = M - 1;
    const ushort* aptr = A + (size_t)arow * IN_DIM + (lane >> 4) * 8;
    bf16x8 af[5];
    #pragma unroll
    for (int kb = 0; kb < 5; ++kb) af[kb] = *(const bf16x8*)(aptr + kb * 32);
    const bf16x8* b1 = (const bf16x8*)B1;
    const bf16x8* b2 = (const bf16x8*)B2;
    const bf16x8* b3 = (const bf16x8*)B3;
    f32x4 aL[16] = {}, aR[16] = {}, aS[4] = {};
    #pragma unroll
    for (int kb = 0; kb < 5; ++kb) {
        #pragma unroll
        for (int t = 0; t < 16; ++t)
            aL[t] = __builtin_amdgcn_mfma_f32_16x16x32_bf16(af[kb], b1[(kb * 16 + t) * 64 + lane], aL[t], 0, 0, 0);
        #pragma unroll
        for (int t = 0; t < 16; ++t)
            aR[t] = __builtin_amdgcn_mfma_f32_16x16x32_bf16(af[kb], b2[(kb * 16 + t) * 64 + lane], aR[t], 0, 0, 0);
        #pragma unroll
        for (int t = 0; t < 4; ++t)
            aS[t] = __builtin_amdgcn_mfma_f32_16x16x32_bf16(af[kb], b3[(kb * 4 + t) * 64 + lane], aS[t], 0, 0, 0);
    }
    const int cn = lane & 15, cq = lane >> 4;
    #pragma unroll
    for (int t = 0; t < 16; ++t) {
        float bbL = b2f(bi1[t * 16 + cn]);
        float bbR = b2f(bi2[t * 16 + cn]);
        #pragma unroll
        for (int r = 0; r < 4; ++r) {
            int grow = row0 + cq * 4 + r;
            if (grow < M) {
                o1[(size_t)grow * C1 + t * 16 + cn] = f2b(aL[t][r] + bbL);
                o2[(size_t)grow * C1 + t * 16 + cn] = f2b(aR[t][r] + bbR);
            }
        }
    }
    #pragma unroll
    for (int t = 0; t < 4; ++t) {
        float bb = b2f(bi3[t * 16 + cn]);
        #pragma unroll
        for (int r = 0; r < 4; ++r) {
            int grow = row0 + cq * 4 + r;
            if (grow < M)
                o3[(size_t)grow * HID + t * 16 + cn] = f2b(aS[t][r] + bb);
        }
    }
}

// ---------------- fused layer-2 MFMA GEMM: xl2(64) + xr2(64), K=256 ----------------
__global__ __launch_bounds__(256) void gemm2_k(const ushort* __restrict__ A,
                                               const ushort* __restrict__ B1,
                                               const ushort* __restrict__ B2,
                                               const ushort* __restrict__ bi1,
                                               const ushort* __restrict__ bi2,
                                               ushort* __restrict__ o1,
                                               ushort* __restrict__ o2,
                                               int M) {
    const int wave = threadIdx.x >> 6;
    const int lane = threadIdx.x & 63;
    const int row0 = blockIdx.x * 64 + wave * 16;
    if (row0 >= M) return;
    int arow = row0 + (lane & 15);
    if (arow >= M) arow = M - 1;
    const ushort* aptr = A + (size_t)arow * C1 + (lane >> 4) * 8;
    const bf16x8* b1 = (const bf16x8*)B1;
    const bf16x8* b2 = (const bf16x8*)B2;
    f32x4 aL[4] = {}, aR[4] = {};
    #pragma unroll
    for (int kb = 0; kb < 8; ++kb) {
        bf16x8 af = *(const bf16x8*)(aptr + kb * 32);
        #pragma unroll
        for (int t = 0; t < 4; ++t)
            aL[t] = __builtin_amdgcn_mfma_f32_16x16x32_bf16(af, b1[(kb * 4 + t) * 64 + lane], aL[t], 0, 0, 0);
        #pragma unroll
        for (int t = 0; t < 4; ++t)
            aR[t] = __builtin_amdgcn_mfma_f32_16x16x32_bf16(af, b2[(kb * 4 + t) * 64 + lane], aR[t], 0, 0, 0);
    }
    const int cn = lane & 15, cq = lane >> 4;
    #pragma unroll
    for (int t = 0; t < 4; ++t) {
        float bbL = b2f(bi1[t * 16 + cn]);
        float bbR = b2f(bi2[t * 16 + cn]);
        #pragma unroll
        for (int r = 0; r < 4; ++r) {
            int grow = row0 + cq * 4 + r;
            if (grow < M) {
                o1[(size_t)grow * HID + t * 16 + cn] = f2b(aL[t][r] + bbL);
                o2[(size_t)grow * HID + t * 16 + cn] = f2b(aR[t][r] + bbR);
            }
        }
    }
}

// ---------------- conv1: 8 edges/trip, 16 lanes/edge, 4 ch/lane, DPP reduce ----------------
__global__ __launch_bounds__(256) void conv1_k(const ushort* __restrict__ xl,
                                               const ushort* __restrict__ xr,
                                               const int* __restrict__ row_ptr,
                                               const int* __restrict__ col,
                                               const ushort* __restrict__ att,
                                               const ushort* __restrict__ bias1,
                                               const ushort* __restrict__ g1,
                                               const ushort* __restrict__ b1,
                                               const ushort* __restrict__ m1,
                                               const ushort* __restrict__ v1,
                                               ushort* __restrict__ h1out) {
    const int n = blockIdx.x;
    const int h = threadIdx.x >> 6;          // wave = head
    const int lane = threadIdx.x & 63;
    const int grp = lane >> 4;               // edge slot 0..3
    const int m = lane & 15;                 // channel quad
    const int cpi = h * 16 + m;              // uint2 index within 64-uint2 row
    const uint2* xl2v = (const uint2*)xl;
    const uint2 xru = ((const uint2*)xr)[(size_t)n * 64 + cpi];
    const float xr0 = lo16(xru.x), xr1 = hi16(xru.x);
    const float xr2 = lo16(xru.y), xr3 = hi16(xru.y);
    const uint2 atu = ((const uint2*)att)[cpi];
    const float at0 = lo16(atu.x), at1 = hi16(atu.x);
    const float at2 = lo16(atu.y), at3 = hi16(atu.y);
    const int e0 = row_ptr[n], e1 = row_ptr[n + 1];
    float a0 = 0.f, a1 = 0.f, a2 = 0.f, a3 = 0.f, den = 0.f;
    const int jA = e0 + grp, jB = e0 + 4 + grp;
    int sA = col[jA < e1 ? jA : e1 - 1];
    int sB = col[jB < e1 ? jB : e1 - 1];
    for (int i = e0; i < e1; i += 8) {
        const uint2 xuA = xl2v[(size_t)sA * 64 + cpi];
        const uint2 xuB = xl2v[(size_t)sB * 64 + cpi];
        const int jC = i + 8 + grp, jD = i + 12 + grp;
        const int sC = col[jC < e1 ? jC : e1 - 1];
        const int sD = col[jD < e1 ? jD : e1 - 1];
        const bool vA = (i + grp) < e1, vB = (i + 4 + grp) < e1;
        // edge A
        const float xa0 = lo16(xuA.x), xa1 = hi16(xuA.x);
        const float xa2 = lo16(xuA.y), xa3 = hi16(xuA.y);
        float ta0 = xa0 + xr0; ta0 = fmaxf(ta0, ta0 * NEG_SLOPE);
        float ta1 = xa1 + xr1; ta1 = fmaxf(ta1, ta1 * NEG_SLOPE);
        float ta2 = xa2 + xr2; ta2 = fmaxf(ta2, ta2 * NEG_SLOPE);
        float ta3 = xa3 + xr3; ta3 = fmaxf(ta3, ta3 * NEG_SLOPE);
        float pA = fmaf(ta0, at0, fmaf(ta1, at1, fmaf(ta2, at2, ta3 * at3)));
        pA = row16_sum(pA);
        const float wA = vA ? __expf(fminf(pA, 60.f)) : 0.f;
        // edge B
        const float xb0 = lo16(xuB.x), xb1 = hi16(xuB.x);
        const float xb2 = lo16(xuB.y), xb3 = hi16(xuB.y);
        float tb0 = xb0 + xr0; tb0 = fmaxf(tb0, tb0 * NEG_SLOPE);
        float tb1 = xb1 + xr1; tb1 = fmaxf(tb1, tb1 * NEG_SLOPE);
        float tb2 = xb2 + xr2; tb2 = fmaxf(tb2, tb2 * NEG_SLOPE);
        float tb3 = xb3 + xr3; tb3 = fmaxf(tb3, tb3 * NEG_SLOPE);
        float pB = fmaf(tb0, at0, fmaf(tb1, at1, fmaf(tb2, at2, tb3 * at3)));
        pB = row16_sum(pB);
        const float wB = vB ? __expf(fminf(pB, 60.f)) : 0.f;
        // accumulate
        a0 = fmaf(wA, xa0, a0); a0 = fmaf(wB, xb0, a0);
        a1 = fmaf(wA, xa1, a1); a1 = fmaf(wB, xb1, a1);
        a2 = fmaf(wA, xa2, a2); a2 = fmaf(wB, xb2, a2);
        a3 = fmaf(wA, xa3, a3); a3 = fmaf(wB, xb3, a3);
        den += wA + wB;
        sA = sC; sB = sD;
    }
    a0 += __shfl_xor(a0, 16); a0 += __shfl_xor(a0, 32);
    a1 += __shfl_xor(a1, 16); a1 += __shfl_xor(a1, 32);
    a2 += __shfl_xor(a2, 16); a2 += __shfl_xor(a2, 32);
    a3 += __shfl_xor(a3, 16); a3 += __shfl_xor(a3, 32);
    den += __shfl_xor(den, 16); den += __shfl_xor(den, 32);
    if (lane < 16) {
        const float inv = 1.f / den;
        const uint2 biu = ((const uint2*)bias1)[cpi];
        const uint2 gu  = ((const uint2*)g1)[cpi];
        const uint2 bu  = ((const uint2*)b1)[cpi];
        const uint2 mu  = ((const uint2*)m1)[cpi];
        const uint2 vu  = ((const uint2*)v1)[cpi];
        float o0 = fmaf(a0, inv, lo16(biu.x));
        float o1 = fmaf(a1, inv, hi16(biu.x));
        float o2 = fmaf(a2, inv, lo16(biu.y));
        float o3 = fmaf(a3, inv, hi16(biu.y));
        float s0 = lo16(gu.x) * rsqrtf(lo16(vu.x) + BN_EPS);
        float s1 = hi16(gu.x) * rsqrtf(hi16(vu.x) + BN_EPS);
        float s2 = lo16(gu.y) * rsqrtf(lo16(vu.y) + BN_EPS);
        float s3 = hi16(gu.y) * rsqrtf(hi16(vu.y) + BN_EPS);
        float h0 = fmaxf((o0 - lo16(mu.x)) * s0 + lo16(bu.x), 0.f);
        float h1v = fmaxf((o1 - hi16(mu.x)) * s1 + hi16(bu.x), 0.f);
        float h2 = fmaxf((o2 - lo16(mu.y)) * s2 + lo16(bu.y), 0.f);
        float h3 = fmaxf((o3 - hi16(mu.y)) * s3 + hi16(bu.y), 0.f);
        uint2 ou;
        ou.x = (uint)f2b(h0) | ((uint)f2b(h1v) << 16);
        ou.y = (uint)f2b(h2) | ((uint)f2b(h3) << 16);
        ((uint2*)h1out)[(size_t)n * 64 + cpi] = ou;
    }
}

// ---------------- conv2 + BN2 + relu + skip + output linear ----------------
__global__ __launch_bounds__(256) void conv2_k(const ushort* __restrict__ xl,
                                               const ushort* __restrict__ xr,
                                               const ushort* __restrict__ xskip,
                                               const int* __restrict__ row_ptr,
                                               const int* __restrict__ col,
                                               const ushort* __restrict__ att2,
                                               const ushort* __restrict__ bias2,
                                               const ushort* __restrict__ g2,
                                               const ushort* __restrict__ bb2,
                                               const ushort* __restrict__ m2,
                                               const ushort* __restrict__ v2,
                                               const ushort* __restrict__ Wo,
                                               const ushort* __restrict__ bo,
                                               void* __restrict__ out,
                                               const int* __restrict__ flags) {
    const int n = blockIdx.x * 4 + (threadIdx.x >> 6);
    if (n >= N_NODES) return;
    const int lane = threadIdx.x & 63;
    const int grp = lane >> 4;
    const int m = lane & 15;                 // uint2 index within 16-uint2 row
    const uint2* xl2v = (const uint2*)xl;
    const uint2 xru = ((const uint2*)xr)[(size_t)n * 16 + m];
    const float xr0 = lo16(xru.x), xr1 = hi16(xru.x);
    const float xr2 = lo16(xru.y), xr3 = hi16(xru.y);
    const uint2 atu = ((const uint2*)att2)[m];
    const float at0 = lo16(atu.x), at1 = hi16(atu.x);
    const float at2 = lo16(atu.y), at3 = hi16(atu.y);
    const int e0 = row_ptr[n], e1 = row_ptr[n + 1];
    float a0 = 0.f, a1 = 0.f, a2 = 0.f, a3 = 0.f, den = 0.f;
    const int jA = e0 + grp, jB = e0 + 4 + grp;
    int sA = col[jA < e1 ? jA : e1 - 1];
    int sB = col[jB < e1 ? jB : e1 - 1];
    for (int i = e0; i < e1; i += 8) {
        const uint2 xuA = xl2v[(size_t)sA * 16 + m];
        const uint2 xuB = xl2v[(size_t)sB * 16 + m];
        const int jC = i + 8 + grp, jD = i + 12 + grp;
        const int sC = col[jC < e1 ? jC : e1 - 1];
        const int sD = col[jD < e1 ? jD : e1 - 1];
        const bool vA = (i + grp) < e1, vB = (i + 4 + grp) < e1;
        const float xa0 = lo16(xuA.x), xa1 = hi16(xuA.x);
        const float xa2 = lo16(xuA.y), xa3 = hi16(xuA.y);
        float ta0 = xa0 + xr0; ta0 = fmaxf(ta0, ta0 * NEG_SLOPE);
        float ta1 = xa1 + xr1; ta1 = fmaxf(ta1, ta1 * NEG_SLOPE);
        float ta2 = xa2 + xr2; ta2 = fmaxf(ta2, ta2 * NEG_SLOPE);
        float ta3 = xa3 + xr3; ta3 = fmaxf(ta3, ta3 * NEG_SLOPE);
        float pA = fmaf(ta0, at0, fmaf(ta1, at1, fmaf(ta2, at2, ta3 * at3)));
        pA = row16_sum(pA);
        const float wA = vA ? __expf(fminf(pA, 60.f)) : 0.f;
        const float xb0 = lo16(xuB.x), xb1 = hi16(xuB.x);
        const float xb2 = lo16(xuB.y), xb3 = hi16(xuB.y);
        float tb0 = xb0 + xr0; tb0 = fmaxf(tb0, tb0 * NEG_SLOPE);
        float tb1 = xb1 + xr1; tb1 = fmaxf(tb1, tb1 * NEG_SLOPE);
        float tb2 = xb2 + xr2; tb2 = fmaxf(tb2, tb2 * NEG_SLOPE);
        float tb3 = xb3 + xr3; tb3 = fmaxf(tb3, tb3 * NEG_SLOPE);
        float pB = fmaf(tb0, at0, fmaf(tb1, at1, fmaf(tb2, at2, tb3 * at3)));
        pB = row16_sum(pB);
        const float wB = vB ? __expf(fminf(pB, 60.f)) : 0.f;
        a0 = fmaf(wA, xa0, a0); a0 = fmaf(wB, xb0, a0);
        a1 = fmaf(wA, xa1, a1); a1 = fmaf(wB, xb1, a1);
        a2 = fmaf(wA, xa2, a2); a2 = fmaf(wB, xb2, a2);
        a3 = fmaf(wA, xa3, a3); a3 = fmaf(wB, xb3, a3);
        den += wA + wB;
        sA = sC; sB = sD;
    }
    a0 += __shfl_xor(a0, 16); a0 += __shfl_xor(a0, 32);
    a1 += __shfl_xor(a1, 16); a1 += __shfl_xor(a1, 32);
    a2 += __shfl_xor(a2, 16); a2 += __shfl_xor(a2, 32);
    a3 += __shfl_xor(a3, 16); a3 += __shfl_xor(a3, 32);
    den += __shfl_xor(den, 16); den += __shfl_xor(den, 32);
    if (lane < 16) {
        const float inv = 1.f / den;
        const uint2 biu = ((const uint2*)bias2)[m];
        const uint2 gu  = ((const uint2*)g2)[m];
        const uint2 bu  = ((const uint2*)bb2)[m];
        const uint2 mu  = ((const uint2*)m2)[m];
        const uint2 vu  = ((const uint2*)v2)[m];
        const uint2 sku = ((const uint2*)xskip)[(size_t)n * 16 + m];
        const uint2 wou = ((const uint2*)Wo)[m];
        float o0 = fmaf(a0, inv, lo16(biu.x));
        float o1 = fmaf(a1, inv, hi16(biu.x));
        float o2 = fmaf(a2, inv, lo16(biu.y));
        float o3 = fmaf(a3, inv, hi16(biu.y));
        float s0 = lo16(gu.x) * rsqrtf(lo16(vu.x) + BN_EPS);
        float s1 = hi16(gu.x) * rsqrtf(hi16(vu.x) + BN_EPS);
        float s2 = lo16(gu.y) * rsqrtf(lo16(vu.y) + BN_EPS);
        float s3 = hi16(gu.y) * rsqrtf(hi16(vu.y) + BN_EPS);
        float h0 = fmaxf((o0 - lo16(mu.x)) * s0 + lo16(bu.x), 0.f) + lo16(sku.x);
        float h1v = fmaxf((o1 - hi16(mu.x)) * s1 + hi16(bu.x), 0.f) + hi16(sku.x);
        float h2 = fmaxf((o2 - lo16(mu.y)) * s2 + lo16(bu.y), 0.f) + lo16(sku.y);
        float h3 = fmaxf((o3 - hi16(mu.y)) * s3 + hi16(bu.y), 0.f) + hi16(sku.y);
        float d = fmaf(h0, lo16(wou.x), fmaf(h1v, hi16(wou.x),
                  fmaf(h2, lo16(wou.y), h3 * hi16(wou.y))));
        d = row16_sum(d);
        if (m == 0) {
            float r = d + b2f(bo[0]);
            if (flags[0]) ((float*)out)[n] = r;
            else          ((ushort*)out)[n] = f2b(r);
        }
    }
}

extern "C" void kernel_launch(void* const* d_in, const int* in_sizes, int n_in,
                              void* d_out, int out_size, void* d_ws, size_t ws_size,
                              hipStream_t stream) {
    char* ws = (char*)d_ws;
    size_t off = 0;
    auto alloc = [&](size_t bytes) -> void* {
        void* p = ws + off;
        off += (bytes + 255) & ~(size_t)255;
        return p;
    };
    int*    flags   = (int*)alloc(256);
    ushort* params  = (ushort*)alloc((size_t)127617 * 2);
    ushort* x_c     = (ushort*)alloc((size_t)N_NODES * IN_DIM * 2);
    int*    row_ptr = (int*)alloc((size_t)(N_NODES + 1) * 4);
    int*    rowcur  = (int*)alloc((size_t)N_NODES * 4);
    int*    deg     = (int*)alloc((size_t)N_NODES * 4);
    int*    colbuf  = (int*)alloc((size_t)EP_EDGES * 4);
    int*    bsum    = (int*)alloc(64 * 4);
    ushort* xl1     = (ushort*)alloc((size_t)N_NODES * C1 * 2);
    ushort* xr1     = (ushort*)alloc((size_t)N_NODES * C1 * 2);
    ushort* xskip   = (ushort*)alloc((size_t)N_NODES * HID * 2);
    ushort* h1      = (ushort*)alloc((size_t)N_NODES * C1 * 2);
    ushort* xl2     = (ushort*)alloc((size_t)N_NODES * HID * 2);
    ushort* xr2     = (ushort*)alloc((size_t)N_NODES * HID * 2);
    ushort* swzWl1  = (ushort*)alloc((size_t)IN_DIM * C1 * 2);
    ushort* swzWr1  = (ushort*)alloc((size_t)IN_DIM * C1 * 2);
    ushort* swzWs   = (ushort*)alloc((size_t)IN_DIM * HID * 2);
    ushort* swzWl2  = (ushort*)alloc((size_t)C1 * HID * 2);
    ushort* swzWr2  = (ushort*)alloc((size_t)C1 * HID * 2);

    ushort* Wl1c   = params + 0;
    ushort* bl1c   = params + 40960;
    ushort* Wr1c   = params + 41216;
    ushort* br1c   = params + 82176;
    ushort* att1c  = params + 82432;
    ushort* bias1c = params + 82688;
    ushort* g1c    = params + 82944;
    ushort* b1c    = params + 83200;
    ushort* m1c    = params + 83456;
    ushort* v1c    = params + 83712;
    ushort* Wl2c   = params + 83968;
    ushort* bl2c   = params + 100352;
    ushort* Wr2c   = params + 100416;
    ushort* br2c   = params + 116800;
    ushort* att2c  = params + 116864;
    ushort* bias2c = params + 116928;
    ushort* g2c    = params + 116992;
    ushort* b2c    = params + 117056;
    ushort* m2c    = params + 117120;
    ushort* v2c    = params + 117184;
    ushort* Wsc    = params + 117248;
    ushort* bsc    = params + 127488;
    ushort* Woc    = params + 127552;
    ushort* boc    = params + 127616;

    // ---- detect dtypes & canonicalize ----
    detect_k<<<1, 64, 0, stream>>>((const ushort*)d_in[0], (const int*)d_in[1], flags);
    cvt_x_k<<<(N_NODES * IN_DIM + 255) / 256, 256, 0, stream>>>(d_in[0], x_c, flags, deg);
    PP pp;
    for (int i = 0; i < 24; ++i) pp.p[i] = d_in[2 + i];
    cvt_params_k<<<24, 256, 0, stream>>>(pp, params, flags);

    // ---- fused weight swizzles for MFMA ----
    SWZ sw;
    sw.W[0] = Wl1c;  sw.D[0] = swzWl1; sw.NT[0] = 16; sw.base[0] = 0;
    sw.W[1] = Wr1c;  sw.D[1] = swzWr1; sw.NT[1] = 16; sw.base[1] = 5120;
    sw.W[2] = Wsc;   sw.D[2] = swzWs;  sw.NT[2] = 4;  sw.base[2] = 10240;
    sw.W[3] = Wl2c;  sw.D[3] = swzWl2; sw.NT[3] = 4;  sw.base[3] = 11520;
    sw.W[4] = Wr2c;  sw.D[4] = swzWr2; sw.NT[4] = 4;  sw.base[4] = 13568;
    sw.total = 15616;
    swz_all_k<<<(15616 + 255) / 256, 256, 0, stream>>>(sw);

    const int NB_N = (N_NODES + 255) / 256;        // 196
    const int NB_E = (EP_EDGES + 255) / 256;       // 3321
    const int NB_S = (N_NODES + 1023) / 1024;      // 49

    // ---- CSR build (reads raw edge_index) ----
    const int* ei_raw = (const int*)d_in[1];
    hist_k<<<NB_E, 256, 0, stream>>>(ei_raw, flags, deg);
    scan1_k<<<NB_S, 1024, 0, stream>>>(deg, row_ptr, bsum);
    scan2_k<<<1, 64, 0, stream>>>(bsum, NB_S);
    scan3_k<<<NB_N, 256, 0, stream>>>(row_ptr, bsum, rowcur);
    scatter_k<<<NB_E, 256, 0, stream>>>(ei_raw, flags, rowcur, colbuf);

    // ---- layer-1 linear transforms (+ skip), fused MFMA ----
    const int GB = (N_NODES + 63) / 64;  // 782 blocks of 4 waves x 16 rows
    gemm3_k<<<GB, 256, 0, stream>>>(x_c, swzWl1, swzWr1, swzWs, bl1c, br1c, bsc,
                                    xl1, xr1, xskip, N_NODES);

    // ---- conv1 edge aggregation + BN1 + relu ----
    conv1_k<<<N_NODES, 256, 0, stream>>>(xl1, xr1, row_ptr, colbuf, att1c, bias1c,
                                         g1c, b1c, m1c, v1c, h1);

    // ---- layer-2 linear transforms, fused MFMA ----
    gemm2_k<<<GB, 256, 0, stream>>>(h1, swzWl2, swzWr2, bl2c, br2c, xl2, xr2, N_NODES);

    // ---- conv2 + BN2 + relu + skip + output linear ----
    conv2_k<<<(N_NODES + 3) / 4, 256, 0, stream>>>(xl2, xr2, xskip, row_ptr, colbuf,
                                                   att2c, bias2c, g2c, b2c, m2c, v2c,
                                                   Woc, boc, d_out, flags);
}